// Round 2
// baseline (2078.560 us; speedup 1.0000x reference)
//
#include <hip/hip_runtime.h>
#include <math.h>

constexpr int CB  = 8;       // batch
constexpr int CN  = 4096;    // tokens
constexpr int CC  = 640;     // channels
constexpr int CNH = 5;       // heads
constexpr int CHD = 128;     // head dim
constexpr int CM  = CB * CN; // 32768 rows
constexpr float CEPS = 1e-6f;
constexpr int NCH = 8;       // n-chunks for kv2 partials

// ---------------- softplus of scale ----------------
__global__ void softplus_k(const float* __restrict__ scale, float* __restrict__ sc) {
    int t = threadIdx.x;
    if (t < CC) sc[t] = log1pf(expf(scale[t]));
}

// ------- generic f32 GEMM: C[M,N] = A[M,K] * B[N,K]^T (+bias) -------
template<bool BIAS>
__global__ __launch_bounds__(256) void gemm_f32(const float* __restrict__ A,
                                                const float* __restrict__ Bw,
                                                float* __restrict__ Co,
                                                const float* __restrict__ bias,
                                                int Mr, int Nr, int Kr) {
    __shared__ float As[16][132];
    __shared__ float Bs[16][132];
    const int t  = threadIdx.x;
    const int m0 = blockIdx.y * 128;
    const int n0 = blockIdx.x * 128;
    const int lrow = t >> 1;
    const int lk   = (t & 1) * 8;
    const int tx = t & 15, ty = t >> 4;
    float acc[8][8];
    #pragma unroll
    for (int i = 0; i < 8; ++i)
        #pragma unroll
        for (int j = 0; j < 8; ++j) acc[i][j] = 0.f;

    const float* ap = A  + (size_t)(m0 + lrow) * Kr + lk;
    const float* bp = Bw + (size_t)(n0 + lrow) * Kr + lk;
    for (int k0 = 0; k0 < Kr; k0 += 16) {
        float4 a0 = *(const float4*)(ap + k0);
        float4 a1 = *(const float4*)(ap + k0 + 4);
        float4 b0 = *(const float4*)(bp + k0);
        float4 b1 = *(const float4*)(bp + k0 + 4);
        __syncthreads();
        As[lk+0][lrow]=a0.x; As[lk+1][lrow]=a0.y; As[lk+2][lrow]=a0.z; As[lk+3][lrow]=a0.w;
        As[lk+4][lrow]=a1.x; As[lk+5][lrow]=a1.y; As[lk+6][lrow]=a1.z; As[lk+7][lrow]=a1.w;
        Bs[lk+0][lrow]=b0.x; Bs[lk+1][lrow]=b0.y; Bs[lk+2][lrow]=b0.z; Bs[lk+3][lrow]=b0.w;
        Bs[lk+4][lrow]=b1.x; Bs[lk+5][lrow]=b1.y; Bs[lk+6][lrow]=b1.z; Bs[lk+7][lrow]=b1.w;
        __syncthreads();
        #pragma unroll
        for (int kk = 0; kk < 16; ++kk) {
            float4 av0 = *(const float4*)&As[kk][ty*8];
            float4 av1 = *(const float4*)&As[kk][ty*8+4];
            float4 bv0 = *(const float4*)&Bs[kk][tx*8];
            float4 bv1 = *(const float4*)&Bs[kk][tx*8+4];
            float a[8] = {av0.x,av0.y,av0.z,av0.w,av1.x,av1.y,av1.z,av1.w};
            float b[8] = {bv0.x,bv0.y,bv0.z,bv0.w,bv1.x,bv1.y,bv1.z,bv1.w};
            #pragma unroll
            for (int i = 0; i < 8; ++i)
                #pragma unroll
                for (int j = 0; j < 8; ++j)
                    acc[i][j] = fmaf(a[i], b[j], acc[i][j]);
        }
    }
    #pragma unroll
    for (int i = 0; i < 8; ++i) {
        const size_t row = (size_t)(m0 + ty*8 + i);
        float* op = Co + row * Nr + n0 + tx*8;
        float o[8];
        #pragma unroll
        for (int j = 0; j < 8; ++j) o[j] = acc[i][j];
        if (BIAS) {
            const float* bb = bias + n0 + tx*8;
            #pragma unroll
            for (int j = 0; j < 8; ++j) o[j] += bb[j];
        }
        float4 o0, o1;
        o0.x=o[0]; o0.y=o[1]; o0.z=o[2]; o0.w=o[3];
        o1.x=o[4]; o1.y=o[5]; o1.z=o[6]; o1.w=o[7];
        *(float4*)op     = o0;
        *(float4*)(op+4) = o1;
    }
}

// ------- per-row focused transform (q and k, in place) -------
__global__ __launch_bounds__(256) void rowtrans(float* __restrict__ qb, float* __restrict__ kb,
                                                const float* __restrict__ pos,
                                                const float* __restrict__ sc) {
    const int m = blockIdx.x;
    const int n = m & (CN - 1);
    const int t = threadIdx.x;
    float qv[3], kv[3];
    float s2q = 0.f, s6q = 0.f, s2k = 0.f, s6k = 0.f;
    #pragma unroll
    for (int i = 0; i < 3; ++i) {
        int c = t + i * 256;
        if (c < CC) {
            float scv = sc[c];
            float qq = qb[(size_t)m * CC + c];
            qq = (fmaxf(qq, 0.f) + CEPS) / scv;
            float kk = kb[(size_t)m * CC + c] + pos[(size_t)n * CC + c];
            kk = (fmaxf(kk, 0.f) + CEPS) / scv;
            qv[i] = qq; kv[i] = kk;
            float q2 = qq * qq, k2 = kk * kk;
            s2q += q2; s6q += q2 * q2 * q2;
            s2k += k2; s6k += k2 * k2 * k2;
        } else { qv[i] = 0.f; kv[i] = 0.f; }
    }
    // block reduce 4 sums
    #pragma unroll
    for (int o = 32; o > 0; o >>= 1) {
        s2q += __shfl_down(s2q, o);
        s6q += __shfl_down(s6q, o);
        s2k += __shfl_down(s2k, o);
        s6k += __shfl_down(s6k, o);
    }
    __shared__ float red[4][4];
    const int lane = t & 63, w = t >> 6;
    if (lane == 0) { red[0][w] = s2q; red[1][w] = s6q; red[2][w] = s2k; red[3][w] = s6k; }
    __syncthreads();
    float t2q = red[0][0] + red[0][1] + red[0][2] + red[0][3];
    float t6q = red[1][0] + red[1][1] + red[1][2] + red[1][3];
    float t2k = red[2][0] + red[2][1] + red[2][2] + red[2][3];
    float t6k = red[3][0] + red[3][1] + red[3][2] + red[3][3];
    const float qmul = sqrtf(t2q) / sqrtf(t6q);
    const float kmul = sqrtf(t2k) / sqrtf(t6k);
    #pragma unroll
    for (int i = 0; i < 3; ++i) {
        int c = t + i * 256;
        if (c < CC) {
            qb[(size_t)m * CC + c] = qv[i] * qv[i] * qv[i] * qmul;
            kb[(size_t)m * CC + c] = kv[i] * kv[i] * kv[i] * kmul;
        }
    }
}

// ------- kv2 partials: per (bh, chunk): kv2p += K^T V over 512 rows; ksum partial -------
__global__ __launch_bounds__(256) void kv2_partial(const float* __restrict__ kb,
                                                   const float* __restrict__ vb,
                                                   float* __restrict__ kv2p,
                                                   float* __restrict__ ksmp) {
    const int nc = blockIdx.x, bh = blockIdx.y;
    const int b = bh / CNH, h = bh % CNH;
    __shared__ float ks[32][132];
    __shared__ float vs[32][132];
    const int t = threadIdx.x;
    const int tx = t & 15, ty = t >> 4;
    float acc[8][8];
    #pragma unroll
    for (int i = 0; i < 8; ++i)
        #pragma unroll
        for (int j = 0; j < 8; ++j) acc[i][j] = 0.f;
    float ksacc = 0.f;
    const size_t mbase = (size_t)b * CN + (size_t)nc * 512;
    for (int tile = 0; tile < 16; ++tile) {
        const int nt0 = tile * 32;
        __syncthreads();
        #pragma unroll
        for (int r = 0; r < 4; ++r) {
            int idx = t + 256 * r;
            int nn = idx >> 5, c4 = (idx & 31) * 4;
            size_t g = (mbase + nt0 + nn) * CC + h * CHD + c4;
            *(float4*)&ks[nn][c4] = *(const float4*)&kb[g];
            *(float4*)&vs[nn][c4] = *(const float4*)&vb[g];
        }
        __syncthreads();
        #pragma unroll 2
        for (int nn = 0; nn < 32; ++nn) {
            float4 a0 = *(const float4*)&ks[nn][ty*8];
            float4 a1 = *(const float4*)&ks[nn][ty*8+4];
            float4 b0 = *(const float4*)&vs[nn][tx*8];
            float4 b1 = *(const float4*)&vs[nn][tx*8+4];
            float a[8] = {a0.x,a0.y,a0.z,a0.w,a1.x,a1.y,a1.z,a1.w};
            float b[8] = {b0.x,b0.y,b0.z,b0.w,b1.x,b1.y,b1.z,b1.w};
            #pragma unroll
            for (int i = 0; i < 8; ++i)
                #pragma unroll
                for (int j = 0; j < 8; ++j)
                    acc[i][j] = fmaf(a[i], b[j], acc[i][j]);
        }
        if (t < 128) {
            #pragma unroll
            for (int nn = 0; nn < 32; ++nn) ksacc += ks[nn][t];
        }
    }
    float* outp = kv2p + ((size_t)bh * NCH + nc) * 16384;
    #pragma unroll
    for (int i = 0; i < 8; ++i) {
        float4 o0, o1;
        o0.x=acc[i][0]; o0.y=acc[i][1]; o0.z=acc[i][2]; o0.w=acc[i][3];
        o1.x=acc[i][4]; o1.y=acc[i][5]; o1.z=acc[i][6]; o1.w=acc[i][7];
        *(float4*)&outp[(ty*8+i)*128 + tx*8]     = o0;
        *(float4*)&outp[(ty*8+i)*128 + tx*8 + 4] = o1;
    }
    if (t < 128) ksmp[((size_t)bh * NCH + nc) * 128 + t] = ksacc;
}

// ------- reduce partials -------
__global__ __launch_bounds__(256) void kv2_reduce(const float* __restrict__ kv2p,
                                                  const float* __restrict__ ksmp,
                                                  float* __restrict__ kv2,
                                                  float* __restrict__ ksm) {
    const int bh = blockIdx.x, t = threadIdx.x;
    for (int e = t; e < 16384; e += 256) {
        float s = 0.f;
        #pragma unroll
        for (int nc = 0; nc < NCH; ++nc) s += kv2p[((size_t)bh * NCH + nc) * 16384 + e];
        kv2[(size_t)bh * 16384 + e] = s;
    }
    if (t < 128) {
        float s = 0.f;
        #pragma unroll
        for (int nc = 0; nc < NCH; ++nc) s += ksmp[((size_t)bh * NCH + nc) * 128 + t];
        ksm[(size_t)bh * 128 + t] = s;
    }
}

// ------- attention out: x = (q@kv2)*z, written in place over q -------
__global__ __launch_bounds__(256) void attn_out(float* __restrict__ qb,
                                                const float* __restrict__ kv2,
                                                const float* __restrict__ ksm) {
    const int nb = blockIdx.x, bh = blockIdx.y;
    const int b = bh / CNH, h = bh % CNH;
    __shared__ float kvs[16384];
    __shared__ float qs[64][129];
    __shared__ float kss[128];
    const int t = threadIdx.x;
    const size_t m0 = (size_t)b * CN + (size_t)nb * 64;
    // stage kv2 (64KB) and ksum
    #pragma unroll
    for (int i = 0; i < 16; ++i) {
        int f4 = t + 256 * i;
        *(float4*)&kvs[f4 * 4] = *(const float4*)&kv2[(size_t)bh * 16384 + f4 * 4];
    }
    if (t < 128) kss[t] = ksm[(size_t)bh * 128 + t];
    // stage q tile (64 rows x 128)
    #pragma unroll
    for (int i = 0; i < 8; ++i) {
        int f4 = t + 256 * i;           // < 2048
        int row = f4 >> 5, c4 = (f4 & 31) * 4;
        float4 qv = *(const float4*)&qb[(m0 + row) * CC + h * CHD + c4];
        qs[row][c4] = qv.x; qs[row][c4+1] = qv.y; qs[row][c4+2] = qv.z; qs[row][c4+3] = qv.w;
    }
    __syncthreads();
    const int r = t & 63, dg = t >> 6;
    float zdot = 0.f;
    for (int c = 0; c < 128; ++c) zdot += qs[r][c] * kss[c];
    const float z = 1.f / (zdot + CEPS);
    float acc[32];
    #pragma unroll
    for (int j = 0; j < 32; ++j) acc[j] = 0.f;
    #pragma unroll 4
    for (int c = 0; c < 128; ++c) {
        const float qc = qs[r][c];
        const float4* kp = (const float4*)&kvs[c * 128 + dg * 32];
        #pragma unroll
        for (int j4 = 0; j4 < 8; ++j4) {
            float4 kf = kp[j4];
            acc[j4*4+0] = fmaf(qc, kf.x, acc[j4*4+0]);
            acc[j4*4+1] = fmaf(qc, kf.y, acc[j4*4+1]);
            acc[j4*4+2] = fmaf(qc, kf.z, acc[j4*4+2]);
            acc[j4*4+3] = fmaf(qc, kf.w, acc[j4*4+3]);
        }
    }
    __syncthreads();   // all qs reads done
    #pragma unroll
    for (int j = 0; j < 32; ++j) qs[r][dg * 32 + j] = z * acc[j];
    __syncthreads();
    // coalesced write back over q buffer
    #pragma unroll
    for (int i = 0; i < 8; ++i) {
        int f4 = t + 256 * i;           // < 2048
        int row = f4 >> 5, c4 = (f4 & 31) * 4;
        size_t g = (m0 + row) * CC + h * CHD + c4;
        float4 ov;
        ov.x = qs[row][c4];
        ov.y = qs[row][c4+1];
        ov.z = qs[row][c4+2];
        ov.w = qs[row][c4+3];
        *(float4*)&qb[g] = ov;
    }
}

// ------- 5x5 depthwise conv over v as (64,64) maps, ACCUMULATE into xq -------
__global__ __launch_bounds__(256) void dwconv_add(const float* __restrict__ vb,
                                                  const float* __restrict__ w,
                                                  const float* __restrict__ bias,
                                                  float* __restrict__ xq) {
    const int y = blockIdx.x, bh = blockIdx.y;
    const int b = bh / CNH, h = bh % CNH;
    __shared__ float ws_[CHD * 25];
    const int t = threadIdx.x;
    for (int i = t; i < CHD * 25; i += 256) ws_[i] = w[i];
    __syncthreads();
    const int d = t & 127, xh = t >> 7;
    float wr[25];
    #pragma unroll
    for (int i = 0; i < 25; ++i) wr[i] = ws_[d * 25 + i];
    const float bv = bias[d];
    const size_t cbase = (size_t)b * CN * CC + h * CHD + d;
    for (int xi = 0; xi < 32; ++xi) {
        const int x = xi * 2 + xh;
        float acc = bv;
        #pragma unroll
        for (int dy = 0; dy < 5; ++dy) {
            const int yy = y + dy - 2;
            if (yy < 0 || yy >= 64) continue;
            #pragma unroll
            for (int dx = 0; dx < 5; ++dx) {
                const int xx = x + dx - 2;
                if (xx < 0 || xx >= 64) continue;
                acc += vb[cbase + (size_t)(yy * 64 + xx) * CC] * wr[dy * 5 + dx];
            }
        }
        xq[cbase + (size_t)(y * 64 + x) * CC] += acc;
    }
}

extern "C" void kernel_launch(void* const* d_in, const int* in_sizes, int n_in,
                              void* d_out, int out_size, void* d_ws, size_t ws_size,
                              hipStream_t stream) {
    (void)in_sizes; (void)n_in; (void)out_size; (void)ws_size;
    const float* x1    = (const float*)d_in[0];
    const float* x2    = (const float*)d_in[1];
    const float* Wq    = (const float*)d_in[2];
    const float* Wkv   = (const float*)d_in[3];
    const float* Wproj = (const float*)d_in[4];
    const float* bproj = (const float*)d_in[5];
    const float* dwcw  = (const float*)d_in[6];
    const float* dwcb  = (const float*)d_in[7];
    const float* scale = (const float*)d_in[8];
    const float* pos   = (const float*)d_in[9];
    float* out = (float*)d_out;

    float* ws = (float*)d_ws;
    const size_t MC = (size_t)CM * CC;
    // workspace layout (~191.5 MB total):
    float* qbuf = ws;                                            // MC
    float* vbuf = ws + MC;                                       // MC
    float* kv2p = ws + 2 * MC;                                   // 40*8*16384
    float* kv2  = kv2p + (size_t)40 * NCH * 16384;               // 40*16384
    float* ksmp = kv2  + (size_t)40 * 16384;                     // 40*8*128
    float* ksm  = ksmp + (size_t)40 * NCH * 128;                 // 40*128
    float* scb  = ksm  + (size_t)40 * 128;                       // 640
    // k lives in d_out until the final GEMM overwrites it
    float* kbuf = out;

    hipLaunchKernelGGL(softplus_k, dim3(1), dim3(640), 0, stream, scale, scb);
    hipLaunchKernelGGL((gemm_f32<false>), dim3(CC/128, CM/128), dim3(256), 0, stream,
                       x2, Wq, vbuf, (const float*)nullptr, CM, CC, CC);
    hipLaunchKernelGGL((gemm_f32<false>), dim3(CC/128, CM/128), dim3(256), 0, stream,
                       x1, Wkv, kbuf, (const float*)nullptr, CM, CC, CC);
    hipLaunchKernelGGL((gemm_f32<false>), dim3(CC/128, CM/128), dim3(256), 0, stream,
                       x1, Wkv + (size_t)CC * CC, qbuf, (const float*)nullptr, CM, CC, CC);
    hipLaunchKernelGGL(rowtrans, dim3(CM), dim3(256), 0, stream, qbuf, kbuf, pos, scb);
    hipLaunchKernelGGL(kv2_partial, dim3(NCH, 40), dim3(256), 0, stream, kbuf, vbuf, kv2p, ksmp);
    hipLaunchKernelGGL(kv2_reduce, dim3(40), dim3(256), 0, stream, kv2p, ksmp, kv2, ksm);
    hipLaunchKernelGGL(attn_out, dim3(64, 40), dim3(256), 0, stream, qbuf, kv2, ksm);
    hipLaunchKernelGGL(dwconv_add, dim3(64, 40), dim3(256), 0, stream, vbuf, dwcw, dwcb, qbuf);
    hipLaunchKernelGGL((gemm_f32<true>), dim3(CC/128, CM/128), dim3(256), 0, stream,
                       qbuf, Wproj, out, bproj, CM, CC, CC);
}

// Round 4
// 1273.833 us; speedup vs baseline: 1.6317x; 1.6317x over previous
//
#include <hip/hip_runtime.h>
#include <math.h>

constexpr int CB  = 8;       // batch
constexpr int CN  = 4096;    // tokens
constexpr int CC  = 640;     // channels
constexpr int CNH = 5;       // heads
constexpr int CHD = 128;     // head dim
constexpr int CM  = CB * CN; // 32768 rows
constexpr float CEPS = 1e-6f;
constexpr int NCH = 8;       // n-chunks for kv2 partials

typedef __attribute__((ext_vector_type(8))) short bf16x8;
typedef __attribute__((ext_vector_type(4))) float f32x4;

__device__ inline short f2bf(float x) {
    unsigned u = __float_as_uint(x);
    unsigned r = (u + 0x7fffu + ((u >> 16) & 1u)) >> 16;   // RNE, finite data
    return (short)r;
}

// ---------------- softplus of scale ----------------
__global__ void softplus_k(const float* __restrict__ scale, float* __restrict__ sc) {
    int t = threadIdx.x;
    if (t < CC) sc[t] = log1pf(expf(scale[t]));
}

// ------- bf16 MFMA GEMM: C[M,N] = A[M,K] * B[N,K]^T (+bias), f32 in/out -------
// 128x128 tile, BK=32, 256 thr = 4 waves (2x2), 64x64 per wave.
// Reg-staged f32->bf16 cvt, XOR-swizzled LDS: addr = (row*64 + kg*16) ^ ((row&7)<<4)
// applied identically on write and read (XOR over the combined value — no ADD carry!).
template<bool BIAS>
__global__ __launch_bounds__(256) void gemm_bf16(const float* __restrict__ A,
                                                 const float* __restrict__ Bw,
                                                 float* __restrict__ Co,
                                                 const float* __restrict__ bias,
                                                 int Kr, int Nr) {
    __shared__ short lA[4096];   // 128 rows x 32 k, bf16, swizzled
    __shared__ short lB[4096];
    const int t  = threadIdx.x;
    const int m0 = blockIdx.y * 128;
    const int n0 = blockIdx.x * 128;
    const int l  = t & 63, w = t >> 6, wr = w >> 1, wc = w & 1;

    // staging chunk coords: chunk c -> row=c>>2, kg=c&3 (8 bf16 = 16B per chunk)
    const int r0 = t >> 2,         kg0 = t & 3;
    const int r1 = (t + 256) >> 2, kg1 = t & 3;
    const int st0 = (r0 * 64 + kg0 * 16) ^ ((r0 & 7) << 4);
    const int st1 = (r1 * 64 + kg1 * 16) ^ ((r1 & 7) << 4);

    // fragment read offsets (bytes): row = wx*64 + i*16 + (l&15), kg = l>>4
    // base row bits (l&15)*64 + kg*16, XORed as one value; i adds 16 rows = +1024B (disjoint bits)
    const int offA = ((wr * 64 + (l & 15)) * 64 + (l >> 4) * 16) ^ ((l & 7) << 4);
    const int offB = ((wc * 64 + (l & 15)) * 64 + (l >> 4) * 16) ^ ((l & 7) << 4);

    f32x4 acc[4][4];
    #pragma unroll
    for (int i = 0; i < 4; ++i)
        #pragma unroll
        for (int j = 0; j < 4; ++j) acc[i][j] = (f32x4){0.f, 0.f, 0.f, 0.f};

    for (int k0 = 0; k0 < Kr; k0 += 32) {
        // global loads + cvt (before barrier; no LDS touch)
        bf16x8 ha0, ha1, hb0, hb1;
        {
            const float* s = A + (size_t)(m0 + r0) * Kr + k0 + kg0 * 8;
            float4 f0 = *(const float4*)s, f1 = *(const float4*)(s + 4);
            ha0[0]=f2bf(f0.x); ha0[1]=f2bf(f0.y); ha0[2]=f2bf(f0.z); ha0[3]=f2bf(f0.w);
            ha0[4]=f2bf(f1.x); ha0[5]=f2bf(f1.y); ha0[6]=f2bf(f1.z); ha0[7]=f2bf(f1.w);
        }
        {
            const float* s = A + (size_t)(m0 + r1) * Kr + k0 + kg1 * 8;
            float4 f0 = *(const float4*)s, f1 = *(const float4*)(s + 4);
            ha1[0]=f2bf(f0.x); ha1[1]=f2bf(f0.y); ha1[2]=f2bf(f0.z); ha1[3]=f2bf(f0.w);
            ha1[4]=f2bf(f1.x); ha1[5]=f2bf(f1.y); ha1[6]=f2bf(f1.z); ha1[7]=f2bf(f1.w);
        }
        {
            const float* s = Bw + (size_t)(n0 + r0) * Kr + k0 + kg0 * 8;
            float4 f0 = *(const float4*)s, f1 = *(const float4*)(s + 4);
            hb0[0]=f2bf(f0.x); hb0[1]=f2bf(f0.y); hb0[2]=f2bf(f0.z); hb0[3]=f2bf(f0.w);
            hb0[4]=f2bf(f1.x); hb0[5]=f2bf(f1.y); hb0[6]=f2bf(f1.z); hb0[7]=f2bf(f1.w);
        }
        {
            const float* s = Bw + (size_t)(n0 + r1) * Kr + k0 + kg1 * 8;
            float4 f0 = *(const float4*)s, f1 = *(const float4*)(s + 4);
            hb1[0]=f2bf(f0.x); hb1[1]=f2bf(f0.y); hb1[2]=f2bf(f0.z); hb1[3]=f2bf(f0.w);
            hb1[4]=f2bf(f1.x); hb1[5]=f2bf(f1.y); hb1[6]=f2bf(f1.z); hb1[7]=f2bf(f1.w);
        }
        __syncthreads();   // previous iteration's LDS reads done
        *(bf16x8*)((char*)lA + st0) = ha0;
        *(bf16x8*)((char*)lA + st1) = ha1;
        *(bf16x8*)((char*)lB + st0) = hb0;
        *(bf16x8*)((char*)lB + st1) = hb1;
        __syncthreads();
        bf16x8 af[4], bfv[4];
        #pragma unroll
        for (int i = 0; i < 4; ++i) {
            af[i]  = *(const bf16x8*)((const char*)lA + offA + i * 1024);
            bfv[i] = *(const bf16x8*)((const char*)lB + offB + i * 1024);
        }
        #pragma unroll
        for (int i = 0; i < 4; ++i)
            #pragma unroll
            for (int j = 0; j < 4; ++j)
                acc[i][j] = __builtin_amdgcn_mfma_f32_16x16x32_bf16(af[i], bfv[j], acc[i][j], 0, 0, 0);
    }

    // epilogue: D lane mapping col=l&15 (n), row=(l>>4)*4+reg (m)
    #pragma unroll
    for (int j = 0; j < 4; ++j) {
        const int n = n0 + wc * 64 + j * 16 + (l & 15);
        const float bv = BIAS ? bias[n] : 0.f;
        #pragma unroll
        for (int i = 0; i < 4; ++i) {
            const int m = m0 + wr * 64 + i * 16 + (l >> 4) * 4;
            #pragma unroll
            for (int r = 0; r < 4; ++r)
                Co[(size_t)(m + r) * Nr + n] = acc[i][j][r] + bv;
        }
    }
}

// ------- per-row focused transform (q and k, in place) -------
__global__ __launch_bounds__(256) void rowtrans(float* __restrict__ qb, float* __restrict__ kb,
                                                const float* __restrict__ pos,
                                                const float* __restrict__ sc) {
    const int m = blockIdx.x;
    const int n = m & (CN - 1);
    const int t = threadIdx.x;
    float qv[3], kv[3];
    float s2q = 0.f, s6q = 0.f, s2k = 0.f, s6k = 0.f;
    #pragma unroll
    for (int i = 0; i < 3; ++i) {
        int c = t + i * 256;
        if (c < CC) {
            float scv = sc[c];
            float qq = qb[(size_t)m * CC + c];
            qq = (fmaxf(qq, 0.f) + CEPS) / scv;
            float kk = kb[(size_t)m * CC + c] + pos[(size_t)n * CC + c];
            kk = (fmaxf(kk, 0.f) + CEPS) / scv;
            qv[i] = qq; kv[i] = kk;
            float q2 = qq * qq, k2 = kk * kk;
            s2q += q2; s6q += q2 * q2 * q2;
            s2k += k2; s6k += k2 * k2 * k2;
        } else { qv[i] = 0.f; kv[i] = 0.f; }
    }
    #pragma unroll
    for (int o = 32; o > 0; o >>= 1) {
        s2q += __shfl_down(s2q, o);
        s6q += __shfl_down(s6q, o);
        s2k += __shfl_down(s2k, o);
        s6k += __shfl_down(s6k, o);
    }
    __shared__ float red[4][4];
    const int lane = t & 63, w = t >> 6;
    if (lane == 0) { red[0][w] = s2q; red[1][w] = s6q; red[2][w] = s2k; red[3][w] = s6k; }
    __syncthreads();
    float t2q = red[0][0] + red[0][1] + red[0][2] + red[0][3];
    float t6q = red[1][0] + red[1][1] + red[1][2] + red[1][3];
    float t2k = red[2][0] + red[2][1] + red[2][2] + red[2][3];
    float t6k = red[3][0] + red[3][1] + red[3][2] + red[3][3];
    const float qmul = sqrtf(t2q) / sqrtf(t6q);
    const float kmul = sqrtf(t2k) / sqrtf(t6k);
    #pragma unroll
    for (int i = 0; i < 3; ++i) {
        int c = t + i * 256;
        if (c < CC) {
            qb[(size_t)m * CC + c] = qv[i] * qv[i] * qv[i] * qmul;
            kb[(size_t)m * CC + c] = kv[i] * kv[i] * kv[i] * kmul;
        }
    }
}

// ------- kv2 partials: per (bh, chunk): kv2p += K^T V over 512 rows; ksum partial -------
__global__ __launch_bounds__(256) void kv2_partial(const float* __restrict__ kb,
                                                   const float* __restrict__ vb,
                                                   float* __restrict__ kv2p,
                                                   float* __restrict__ ksmp) {
    const int nc = blockIdx.x, bh = blockIdx.y;
    const int b = bh / CNH, h = bh % CNH;
    __shared__ float ks[32][132];
    __shared__ float vs[32][132];
    const int t = threadIdx.x;
    const int tx = t & 15, ty = t >> 4;
    float acc[8][8];
    #pragma unroll
    for (int i = 0; i < 8; ++i)
        #pragma unroll
        for (int j = 0; j < 8; ++j) acc[i][j] = 0.f;
    float ksacc = 0.f;
    const size_t mbase = (size_t)b * CN + (size_t)nc * 512;
    for (int tile = 0; tile < 16; ++tile) {
        const int nt0 = tile * 32;
        __syncthreads();
        #pragma unroll
        for (int r = 0; r < 4; ++r) {
            int idx = t + 256 * r;
            int nn = idx >> 5, c4 = (idx & 31) * 4;
            size_t g = (mbase + nt0 + nn) * CC + h * CHD + c4;
            *(float4*)&ks[nn][c4] = *(const float4*)&kb[g];
            *(float4*)&vs[nn][c4] = *(const float4*)&vb[g];
        }
        __syncthreads();
        #pragma unroll 2
        for (int nn = 0; nn < 32; ++nn) {
            float4 a0 = *(const float4*)&ks[nn][ty*8];
            float4 a1 = *(const float4*)&ks[nn][ty*8+4];
            float4 b0 = *(const float4*)&vs[nn][tx*8];
            float4 b1 = *(const float4*)&vs[nn][tx*8+4];
            float a[8] = {a0.x,a0.y,a0.z,a0.w,a1.x,a1.y,a1.z,a1.w};
            float b[8] = {b0.x,b0.y,b0.z,b0.w,b1.x,b1.y,b1.z,b1.w};
            #pragma unroll
            for (int i = 0; i < 8; ++i)
                #pragma unroll
                for (int j = 0; j < 8; ++j)
                    acc[i][j] = fmaf(a[i], b[j], acc[i][j]);
        }
        if (t < 128) {
            #pragma unroll
            for (int nn = 0; nn < 32; ++nn) ksacc += ks[nn][t];
        }
    }
    float* outp = kv2p + ((size_t)bh * NCH + nc) * 16384;
    #pragma unroll
    for (int i = 0; i < 8; ++i) {
        float4 o0, o1;
        o0.x=acc[i][0]; o0.y=acc[i][1]; o0.z=acc[i][2]; o0.w=acc[i][3];
        o1.x=acc[i][4]; o1.y=acc[i][5]; o1.z=acc[i][6]; o1.w=acc[i][7];
        *(float4*)&outp[(ty*8+i)*128 + tx*8]     = o0;
        *(float4*)&outp[(ty*8+i)*128 + tx*8 + 4] = o1;
    }
    if (t < 128) ksmp[((size_t)bh * NCH + nc) * 128 + t] = ksacc;
}

// ------- reduce partials -------
__global__ __launch_bounds__(256) void kv2_reduce(const float* __restrict__ kv2p,
                                                  const float* __restrict__ ksmp,
                                                  float* __restrict__ kv2,
                                                  float* __restrict__ ksm) {
    const int bh = blockIdx.x, t = threadIdx.x;
    for (int e = t; e < 16384; e += 256) {
        float s = 0.f;
        #pragma unroll
        for (int nc = 0; nc < NCH; ++nc) s += kv2p[((size_t)bh * NCH + nc) * 16384 + e];
        kv2[(size_t)bh * 16384 + e] = s;
    }
    if (t < 128) {
        float s = 0.f;
        #pragma unroll
        for (int nc = 0; nc < NCH; ++nc) s += ksmp[((size_t)bh * NCH + nc) * 128 + t];
        ksm[(size_t)bh * 128 + t] = s;
    }
}

// ------- attention out: x = (q@kv2)*z, written in place over q -------
// kv2 read directly from global (L2-resident, wave-broadcast); LDS = q tile only.
__global__ __launch_bounds__(256) void attn_out(float* __restrict__ qb,
                                                const float* __restrict__ kv2,
                                                const float* __restrict__ ksm) {
    const int nb = blockIdx.x, bh = blockIdx.y;
    const int b = bh / CNH, h = bh % CNH;
    __shared__ float qs[64][129];
    __shared__ float kss[128];
    const int t = threadIdx.x;
    const size_t m0 = (size_t)b * CN + (size_t)nb * 64;
    const float* __restrict__ kvg = kv2 + (size_t)bh * 16384;
    if (t < 128) kss[t] = ksm[(size_t)bh * 128 + t];
    #pragma unroll
    for (int i = 0; i < 8; ++i) {
        int f4 = t + 256 * i;           // < 2048
        int row = f4 >> 5, c4 = (f4 & 31) * 4;
        float4 qv = *(const float4*)&qb[(m0 + row) * CC + h * CHD + c4];
        qs[row][c4] = qv.x; qs[row][c4+1] = qv.y; qs[row][c4+2] = qv.z; qs[row][c4+3] = qv.w;
    }
    __syncthreads();
    const int r = t & 63, dg = t >> 6;   // wave == dg -> broadcast kv2 loads
    float zdot = 0.f;
    for (int c = 0; c < 128; ++c) zdot += qs[r][c] * kss[c];
    const float z = 1.f / (zdot + CEPS);
    float acc[32];
    #pragma unroll
    for (int j = 0; j < 32; ++j) acc[j] = 0.f;
    #pragma unroll 4
    for (int c = 0; c < 128; ++c) {
        const float qc = qs[r][c];
        const float4* kp = (const float4*)(kvg + c * 128 + dg * 32);
        #pragma unroll
        for (int j4 = 0; j4 < 8; ++j4) {
            float4 kf = kp[j4];
            acc[j4*4+0] = fmaf(qc, kf.x, acc[j4*4+0]);
            acc[j4*4+1] = fmaf(qc, kf.y, acc[j4*4+1]);
            acc[j4*4+2] = fmaf(qc, kf.z, acc[j4*4+2]);
            acc[j4*4+3] = fmaf(qc, kf.w, acc[j4*4+3]);
        }
    }
    __syncthreads();   // all qs reads done
    #pragma unroll
    for (int j = 0; j < 32; ++j) qs[r][dg * 32 + j] = z * acc[j];
    __syncthreads();
    #pragma unroll
    for (int i = 0; i < 8; ++i) {
        int f4 = t + 256 * i;           // < 2048
        int row = f4 >> 5, c4 = (f4 & 31) * 4;
        size_t g = (m0 + row) * CC + h * CHD + c4;
        float4 ov;
        ov.x = qs[row][c4];
        ov.y = qs[row][c4+1];
        ov.z = qs[row][c4+2];
        ov.w = qs[row][c4+3];
        *(float4*)&qb[g] = ov;
    }
}

// ------- 5x5 depthwise conv over v as (64,64) maps, ACCUMULATE into xq -------
__global__ __launch_bounds__(256) void dwconv_add(const float* __restrict__ vb,
                                                  const float* __restrict__ w,
                                                  const float* __restrict__ bias,
                                                  float* __restrict__ xq) {
    const int y = blockIdx.x, bh = blockIdx.y;
    const int b = bh / CNH, h = bh % CNH;
    __shared__ float ws_[CHD * 25];
    const int t = threadIdx.x;
    for (int i = t; i < CHD * 25; i += 256) ws_[i] = w[i];
    __syncthreads();
    const int d = t & 127, xh = t >> 7;
    float wr[25];
    #pragma unroll
    for (int i = 0; i < 25; ++i) wr[i] = ws_[d * 25 + i];
    const float bv = bias[d];
    const size_t cbase = (size_t)b * CN * CC + h * CHD + d;
    for (int xi = 0; xi < 32; ++xi) {
        const int x = xi * 2 + xh;
        float acc = bv;
        #pragma unroll
        for (int dy = 0; dy < 5; ++dy) {
            const int yy = y + dy - 2;
            if (yy < 0 || yy >= 64) continue;
            #pragma unroll
            for (int dx = 0; dx < 5; ++dx) {
                const int xx = x + dx - 2;
                if (xx < 0 || xx >= 64) continue;
                acc += vb[cbase + (size_t)(yy * 64 + xx) * CC] * wr[dy * 5 + dx];
            }
        }
        xq[cbase + (size_t)(y * 64 + x) * CC] += acc;
    }
}

extern "C" void kernel_launch(void* const* d_in, const int* in_sizes, int n_in,
                              void* d_out, int out_size, void* d_ws, size_t ws_size,
                              hipStream_t stream) {
    (void)in_sizes; (void)n_in; (void)out_size; (void)ws_size;
    const float* x1    = (const float*)d_in[0];
    const float* x2    = (const float*)d_in[1];
    const float* Wq    = (const float*)d_in[2];
    const float* Wkv   = (const float*)d_in[3];
    const float* Wproj = (const float*)d_in[4];
    const float* bproj = (const float*)d_in[5];
    const float* dwcw  = (const float*)d_in[6];
    const float* dwcb  = (const float*)d_in[7];
    const float* scale = (const float*)d_in[8];
    const float* pos   = (const float*)d_in[9];
    float* out = (float*)d_out;

    float* ws = (float*)d_ws;
    const size_t MC = (size_t)CM * CC;
    // workspace layout (~191.5 MB, unchanged from passing round):
    float* qbuf = ws;                                            // MC
    float* vbuf = ws + MC;                                       // MC
    float* kv2p = ws + 2 * MC;                                   // 40*8*16384
    float* kv2  = kv2p + (size_t)40 * NCH * 16384;               // 40*16384
    float* ksmp = kv2  + (size_t)40 * 16384;                     // 40*8*128
    float* ksm  = ksmp + (size_t)40 * NCH * 128;                 // 40*128
    float* scb  = ksm  + (size_t)40 * 128;                       // 640
    // k lives in d_out until the final GEMM overwrites it
    float* kbuf = out;

    hipLaunchKernelGGL(softplus_k, dim3(1), dim3(640), 0, stream, scale, scb);
    hipLaunchKernelGGL((gemm_bf16<false>), dim3(CC/128, CM/128), dim3(256), 0, stream,
                       x2, Wq, vbuf, (const float*)nullptr, CC, CC);
    hipLaunchKernelGGL((gemm_bf16<false>), dim3(CC/128, CM/128), dim3(256), 0, stream,
                       x1, Wkv, kbuf, (const float*)nullptr, CC, CC);
    hipLaunchKernelGGL((gemm_bf16<false>), dim3(CC/128, CM/128), dim3(256), 0, stream,
                       x1, Wkv + (size_t)CC * CC, qbuf, (const float*)nullptr, CC, CC);
    hipLaunchKernelGGL(rowtrans, dim3(CM), dim3(256), 0, stream, qbuf, kbuf, pos, scb);
    hipLaunchKernelGGL(kv2_partial, dim3(NCH, 40), dim3(256), 0, stream, kbuf, vbuf, kv2p, ksmp);
    hipLaunchKernelGGL(kv2_reduce, dim3(40), dim3(256), 0, stream, kv2p, ksmp, kv2, ksm);
    hipLaunchKernelGGL(attn_out, dim3(64, 40), dim3(256), 0, stream, qbuf, kv2, ksm);
    hipLaunchKernelGGL(dwconv_add, dim3(64, 40), dim3(256), 0, stream, vbuf, dwcw, dwcb, qbuf);
    hipLaunchKernelGGL((gemm_bf16<true>), dim3(CC/128, CM/128), dim3(256), 0, stream,
                       qbuf, Wproj, out, bproj, CC, CC);
}

// Round 5
// 858.393 us; speedup vs baseline: 2.4215x; 1.4840x over previous
//
#include <hip/hip_runtime.h>
#include <math.h>

constexpr int CB  = 8;       // batch
constexpr int CN  = 4096;    // tokens
constexpr int CC  = 640;     // channels
constexpr int CNH = 5;       // heads
constexpr int CHD = 128;     // head dim
constexpr int CM  = CB * CN; // 32768 rows
constexpr float CEPS = 1e-6f;
constexpr int NCH = 8;       // n-chunks for kv2 partials

typedef __attribute__((ext_vector_type(8))) short bf16x8;
typedef __attribute__((ext_vector_type(4))) float f32x4;

__device__ inline short f2bf(float x) {
    unsigned u = __float_as_uint(x);
    unsigned r = (u + 0x7fffu + ((u >> 16) & 1u)) >> 16;   // RNE, finite data
    return (short)r;
}

// ---------------- softplus of scale ----------------
__global__ void softplus_k(const float* __restrict__ scale, float* __restrict__ sc) {
    int t = threadIdx.x;
    if (t < CC) sc[t] = log1pf(expf(scale[t]));
}

// ------- bf16 MFMA GEMM: C[M,N] = A[M,K] * B[N,K]^T (+bias), f32 in/out -------
// 128x128 tile, BK=32, 256 thr = 4 waves (2x2), 64x64 per wave.
// Reg-staged f32->bf16 cvt, XOR-swizzled LDS: addr = (row*64 + kg*16) ^ ((row&7)<<4)
// applied identically on write and read (XOR over the combined value — no ADD carry!).
template<bool BIAS>
__global__ __launch_bounds__(256) void gemm_bf16(const float* __restrict__ A,
                                                 const float* __restrict__ Bw,
                                                 float* __restrict__ Co,
                                                 const float* __restrict__ bias,
                                                 int Kr, int Nr) {
    __shared__ short lA[4096];   // 128 rows x 32 k, bf16, swizzled
    __shared__ short lB[4096];
    const int t  = threadIdx.x;
    const int m0 = blockIdx.y * 128;
    const int n0 = blockIdx.x * 128;
    const int l  = t & 63, w = t >> 6, wr = w >> 1, wc = w & 1;

    const int r0 = t >> 2,         kg0 = t & 3;
    const int r1 = (t + 256) >> 2, kg1 = t & 3;
    const int st0 = (r0 * 64 + kg0 * 16) ^ ((r0 & 7) << 4);
    const int st1 = (r1 * 64 + kg1 * 16) ^ ((r1 & 7) << 4);

    const int offA = ((wr * 64 + (l & 15)) * 64 + (l >> 4) * 16) ^ ((l & 7) << 4);
    const int offB = ((wc * 64 + (l & 15)) * 64 + (l >> 4) * 16) ^ ((l & 7) << 4);

    f32x4 acc[4][4];
    #pragma unroll
    for (int i = 0; i < 4; ++i)
        #pragma unroll
        for (int j = 0; j < 4; ++j) acc[i][j] = (f32x4){0.f, 0.f, 0.f, 0.f};

    for (int k0 = 0; k0 < Kr; k0 += 32) {
        bf16x8 ha0, ha1, hb0, hb1;
        {
            const float* s = A + (size_t)(m0 + r0) * Kr + k0 + kg0 * 8;
            float4 f0 = *(const float4*)s, f1 = *(const float4*)(s + 4);
            ha0[0]=f2bf(f0.x); ha0[1]=f2bf(f0.y); ha0[2]=f2bf(f0.z); ha0[3]=f2bf(f0.w);
            ha0[4]=f2bf(f1.x); ha0[5]=f2bf(f1.y); ha0[6]=f2bf(f1.z); ha0[7]=f2bf(f1.w);
        }
        {
            const float* s = A + (size_t)(m0 + r1) * Kr + k0 + kg1 * 8;
            float4 f0 = *(const float4*)s, f1 = *(const float4*)(s + 4);
            ha1[0]=f2bf(f0.x); ha1[1]=f2bf(f0.y); ha1[2]=f2bf(f0.z); ha1[3]=f2bf(f0.w);
            ha1[4]=f2bf(f1.x); ha1[5]=f2bf(f1.y); ha1[6]=f2bf(f1.z); ha1[7]=f2bf(f1.w);
        }
        {
            const float* s = Bw + (size_t)(n0 + r0) * Kr + k0 + kg0 * 8;
            float4 f0 = *(const float4*)s, f1 = *(const float4*)(s + 4);
            hb0[0]=f2bf(f0.x); hb0[1]=f2bf(f0.y); hb0[2]=f2bf(f0.z); hb0[3]=f2bf(f0.w);
            hb0[4]=f2bf(f1.x); hb0[5]=f2bf(f1.y); hb0[6]=f2bf(f1.z); hb0[7]=f2bf(f1.w);
        }
        {
            const float* s = Bw + (size_t)(n0 + r1) * Kr + k0 + kg1 * 8;
            float4 f0 = *(const float4*)s, f1 = *(const float4*)(s + 4);
            hb1[0]=f2bf(f0.x); hb1[1]=f2bf(f0.y); hb1[2]=f2bf(f0.z); hb1[3]=f2bf(f0.w);
            hb1[4]=f2bf(f1.x); hb1[5]=f2bf(f1.y); hb1[6]=f2bf(f1.z); hb1[7]=f2bf(f1.w);
        }
        __syncthreads();   // previous iteration's LDS reads done
        *(bf16x8*)((char*)lA + st0) = ha0;
        *(bf16x8*)((char*)lA + st1) = ha1;
        *(bf16x8*)((char*)lB + st0) = hb0;
        *(bf16x8*)((char*)lB + st1) = hb1;
        __syncthreads();
        bf16x8 af[4], bfv[4];
        #pragma unroll
        for (int i = 0; i < 4; ++i) {
            af[i]  = *(const bf16x8*)((const char*)lA + offA + i * 1024);
            bfv[i] = *(const bf16x8*)((const char*)lB + offB + i * 1024);
        }
        #pragma unroll
        for (int i = 0; i < 4; ++i)
            #pragma unroll
            for (int j = 0; j < 4; ++j)
                acc[i][j] = __builtin_amdgcn_mfma_f32_16x16x32_bf16(af[i], bfv[j], acc[i][j], 0, 0, 0);
    }

    #pragma unroll
    for (int j = 0; j < 4; ++j) {
        const int n = n0 + wc * 64 + j * 16 + (l & 15);
        const float bv = BIAS ? bias[n] : 0.f;
        #pragma unroll
        for (int i = 0; i < 4; ++i) {
            const int m = m0 + wr * 64 + i * 16 + (l >> 4) * 4;
            #pragma unroll
            for (int r = 0; r < 4; ++r)
                Co[(size_t)(m + r) * Nr + n] = acc[i][j][r] + bv;
        }
    }
}

// ------- per-row focused transform (q and k, in place) -------
__global__ __launch_bounds__(256) void rowtrans(float* __restrict__ qb, float* __restrict__ kb,
                                                const float* __restrict__ pos,
                                                const float* __restrict__ sc) {
    const int m = blockIdx.x;
    const int n = m & (CN - 1);
    const int t = threadIdx.x;
    float qv[3], kv[3];
    float s2q = 0.f, s6q = 0.f, s2k = 0.f, s6k = 0.f;
    #pragma unroll
    for (int i = 0; i < 3; ++i) {
        int c = t + i * 256;
        if (c < CC) {
            float scv = sc[c];
            float qq = qb[(size_t)m * CC + c];
            qq = (fmaxf(qq, 0.f) + CEPS) / scv;
            float kk = kb[(size_t)m * CC + c] + pos[(size_t)n * CC + c];
            kk = (fmaxf(kk, 0.f) + CEPS) / scv;
            qv[i] = qq; kv[i] = kk;
            float q2 = qq * qq, k2 = kk * kk;
            s2q += q2; s6q += q2 * q2 * q2;
            s2k += k2; s6k += k2 * k2 * k2;
        } else { qv[i] = 0.f; kv[i] = 0.f; }
    }
    #pragma unroll
    for (int o = 32; o > 0; o >>= 1) {
        s2q += __shfl_down(s2q, o);
        s6q += __shfl_down(s6q, o);
        s2k += __shfl_down(s2k, o);
        s6k += __shfl_down(s6k, o);
    }
    __shared__ float red[4][4];
    const int lane = t & 63, w = t >> 6;
    if (lane == 0) { red[0][w] = s2q; red[1][w] = s6q; red[2][w] = s2k; red[3][w] = s6k; }
    __syncthreads();
    float t2q = red[0][0] + red[0][1] + red[0][2] + red[0][3];
    float t6q = red[1][0] + red[1][1] + red[1][2] + red[1][3];
    float t2k = red[2][0] + red[2][1] + red[2][2] + red[2][3];
    float t6k = red[3][0] + red[3][1] + red[3][2] + red[3][3];
    const float qmul = sqrtf(t2q) / sqrtf(t6q);
    const float kmul = sqrtf(t2k) / sqrtf(t6k);
    #pragma unroll
    for (int i = 0; i < 3; ++i) {
        int c = t + i * 256;
        if (c < CC) {
            qb[(size_t)m * CC + c] = qv[i] * qv[i] * qv[i] * qmul;
            kb[(size_t)m * CC + c] = kv[i] * kv[i] * kv[i] * kmul;
        }
    }
}

// ------- kv2 partials: per (bh, chunk): kv2p += K^T V over 512 rows; ksum partial -------
__global__ __launch_bounds__(256) void kv2_partial(const float* __restrict__ kb,
                                                   const float* __restrict__ vb,
                                                   float* __restrict__ kv2p,
                                                   float* __restrict__ ksmp) {
    const int nc = blockIdx.x, bh = blockIdx.y;
    const int b = bh / CNH, h = bh % CNH;
    __shared__ float ks[32][132];
    __shared__ float vs[32][132];
    const int t = threadIdx.x;
    const int tx = t & 15, ty = t >> 4;
    float acc[8][8];
    #pragma unroll
    for (int i = 0; i < 8; ++i)
        #pragma unroll
        for (int j = 0; j < 8; ++j) acc[i][j] = 0.f;
    float ksacc = 0.f;
    const size_t mbase = (size_t)b * CN + (size_t)nc * 512;
    for (int tile = 0; tile < 16; ++tile) {
        const int nt0 = tile * 32;
        __syncthreads();
        #pragma unroll
        for (int r = 0; r < 4; ++r) {
            int idx = t + 256 * r;
            int nn = idx >> 5, c4 = (idx & 31) * 4;
            size_t g = (mbase + nt0 + nn) * CC + h * CHD + c4;
            *(float4*)&ks[nn][c4] = *(const float4*)&kb[g];
            *(float4*)&vs[nn][c4] = *(const float4*)&vb[g];
        }
        __syncthreads();
        #pragma unroll 2
        for (int nn = 0; nn < 32; ++nn) {
            float4 a0 = *(const float4*)&ks[nn][ty*8];
            float4 a1 = *(const float4*)&ks[nn][ty*8+4];
            float4 b0 = *(const float4*)&vs[nn][tx*8];
            float4 b1 = *(const float4*)&vs[nn][tx*8+4];
            float a[8] = {a0.x,a0.y,a0.z,a0.w,a1.x,a1.y,a1.z,a1.w};
            float b[8] = {b0.x,b0.y,b0.z,b0.w,b1.x,b1.y,b1.z,b1.w};
            #pragma unroll
            for (int i = 0; i < 8; ++i)
                #pragma unroll
                for (int j = 0; j < 8; ++j)
                    acc[i][j] = fmaf(a[i], b[j], acc[i][j]);
        }
        if (t < 128) {
            #pragma unroll
            for (int nn = 0; nn < 32; ++nn) ksacc += ks[nn][t];
        }
    }
    float* outp = kv2p + ((size_t)bh * NCH + nc) * 16384;
    #pragma unroll
    for (int i = 0; i < 8; ++i) {
        float4 o0, o1;
        o0.x=acc[i][0]; o0.y=acc[i][1]; o0.z=acc[i][2]; o0.w=acc[i][3];
        o1.x=acc[i][4]; o1.y=acc[i][5]; o1.z=acc[i][6]; o1.w=acc[i][7];
        *(float4*)&outp[(ty*8+i)*128 + tx*8]     = o0;
        *(float4*)&outp[(ty*8+i)*128 + tx*8 + 4] = o1;
    }
    if (t < 128) ksmp[((size_t)bh * NCH + nc) * 128 + t] = ksacc;
}

// ------- reduce partials; emit kv2^T as bf16 [d][c] + ksum f32 -------
__global__ __launch_bounds__(256) void kv2_reduce(const float* __restrict__ kv2p,
                                                  const float* __restrict__ ksmp,
                                                  unsigned short* __restrict__ kv2bf,
                                                  float* __restrict__ ksm) {
    const int bh = blockIdx.x, t = threadIdx.x;
    for (int o = t; o < 16384; o += 256) {
        const int d = o >> 7, c = o & 127;
        float s = 0.f;
        #pragma unroll
        for (int nc = 0; nc < NCH; ++nc)
            s += kv2p[((size_t)bh * NCH + nc) * 16384 + c * 128 + d];
        kv2bf[(size_t)bh * 16384 + o] = (unsigned short)f2bf(s);
    }
    if (t < 128) {
        float s = 0.f;
        #pragma unroll
        for (int nc = 0; nc < NCH; ++nc) s += ksmp[((size_t)bh * NCH + nc) * 128 + t];
        ksm[(size_t)bh * 128 + t] = s;
    }
}

// ------- attention out via MFMA: x = (q@kv2)*z, in place over q -------
// Per block: 128 rows x 128 d, K=128. q and kv2^T staged bf16 in swizzled LDS.
// zdot computed in f32 during staging (16-lane shfl reduce vs ksum).
__global__ __launch_bounds__(256) void attn_mfma(float* __restrict__ qb,
                                                 const unsigned short* __restrict__ kv2bf,
                                                 const float* __restrict__ ksm) {
    const int nb = blockIdx.x, bh = blockIdx.y;
    const int b = bh / CNH, h = bh % CNH;
    __shared__ short lQ[16384];    // 128 x 128 bf16, swizzled
    __shared__ short lKV[16384];   // [d][c] bf16, swizzled
    __shared__ float zs[128];
    const int t = threadIdx.x;
    const int l = t & 63, w = t >> 6, wr = w >> 1, wc = w & 1;
    const size_t m0 = (size_t)b * CN + (size_t)nb * 128;

    const int srow0 = t >> 4;      // 0..15
    const int c16   = t & 15;      // 16B chunk within row
    float kreg[8];
    {
        const float* kp = ksm + (size_t)bh * 128 + c16 * 8;
        float4 k0 = *(const float4*)kp, k1 = *(const float4*)(kp + 4);
        kreg[0]=k0.x; kreg[1]=k0.y; kreg[2]=k0.z; kreg[3]=k0.w;
        kreg[4]=k1.x; kreg[5]=k1.y; kreg[6]=k1.z; kreg[7]=k1.w;
    }
    #pragma unroll
    for (int p = 0; p < 8; ++p) {
        const int row = srow0 + p * 16;
        const int st = (row * 256 + c16 * 16) ^ ((row & 7) << 4);
        const float* s = qb + (m0 + row) * CC + h * CHD + c16 * 8;
        float4 f0 = *(const float4*)s, f1 = *(const float4*)(s + 4);
        bf16x8 hq;
        hq[0]=f2bf(f0.x); hq[1]=f2bf(f0.y); hq[2]=f2bf(f0.z); hq[3]=f2bf(f0.w);
        hq[4]=f2bf(f1.x); hq[5]=f2bf(f1.y); hq[6]=f2bf(f1.z); hq[7]=f2bf(f1.w);
        *(bf16x8*)((char*)lQ + st) = hq;
        float zp = f0.x*kreg[0] + f0.y*kreg[1] + f0.z*kreg[2] + f0.w*kreg[3]
                 + f1.x*kreg[4] + f1.y*kreg[5] + f1.z*kreg[6] + f1.w*kreg[7];
        zp += __shfl_xor(zp, 1);
        zp += __shfl_xor(zp, 2);
        zp += __shfl_xor(zp, 4);
        zp += __shfl_xor(zp, 8);
        if (c16 == 0) zs[row] = 1.f / (zp + CEPS);
        bf16x8 hk = *(const bf16x8*)(kv2bf + (size_t)bh * 16384 + row * 128 + c16 * 8);
        *(bf16x8*)((char*)lKV + st) = hk;
    }
    __syncthreads();

    const int baseA = (wr * 64 + (l & 15)) * 256 + ((l >> 4) << 4);
    const int baseB = (wc * 64 + (l & 15)) * 256 + ((l >> 4) << 4);
    const int xorv  = (l & 7) << 4;
    f32x4 acc[4][4];
    #pragma unroll
    for (int i = 0; i < 4; ++i)
        #pragma unroll
        for (int j = 0; j < 4; ++j) acc[i][j] = (f32x4){0.f, 0.f, 0.f, 0.f};

    #pragma unroll
    for (int kk = 0; kk < 4; ++kk) {
        bf16x8 af[4], bv[4];
        #pragma unroll
        for (int i = 0; i < 4; ++i) {
            af[i] = *(const bf16x8*)((const char*)lQ  + (((baseA + kk * 64) ^ xorv) + i * 4096));
            bv[i] = *(const bf16x8*)((const char*)lKV + (((baseB + kk * 64) ^ xorv) + i * 4096));
        }
        #pragma unroll
        for (int i = 0; i < 4; ++i)
            #pragma unroll
            for (int j = 0; j < 4; ++j)
                acc[i][j] = __builtin_amdgcn_mfma_f32_16x16x32_bf16(af[i], bv[j], acc[i][j], 0, 0, 0);
    }

    #pragma unroll
    for (int i = 0; i < 4; ++i) {
        const int mBase = wr * 64 + i * 16 + (l >> 4) * 4;
        float zv[4];
        #pragma unroll
        for (int r = 0; r < 4; ++r) zv[r] = zs[mBase + r];
        #pragma unroll
        for (int j = 0; j < 4; ++j) {
            const int n = wc * 64 + j * 16 + (l & 15);
            float* op = qb + (m0 + mBase) * CC + h * CHD + n;
            #pragma unroll
            for (int r = 0; r < 4; ++r)
                op[(size_t)r * CC] = acc[i][j][r] * zv[r];
        }
    }
}

// ------- 5x5 depthwise conv over v as (64,64) maps, ACCUMULATE into xq -------
__global__ __launch_bounds__(256) void dwconv_add(const float* __restrict__ vb,
                                                  const float* __restrict__ w,
                                                  const float* __restrict__ bias,
                                                  float* __restrict__ xq) {
    const int y = blockIdx.x, bh = blockIdx.y;
    const int b = bh / CNH, h = bh % CNH;
    __shared__ float ws_[CHD * 25];
    const int t = threadIdx.x;
    for (int i = t; i < CHD * 25; i += 256) ws_[i] = w[i];
    __syncthreads();
    const int d = t & 127, xh = t >> 7;
    float wr[25];
    #pragma unroll
    for (int i = 0; i < 25; ++i) wr[i] = ws_[d * 25 + i];
    const float bv = bias[d];
    const size_t cbase = (size_t)b * CN * CC + h * CHD + d;
    for (int xi = 0; xi < 32; ++xi) {
        const int x = xi * 2 + xh;
        float acc = bv;
        #pragma unroll
        for (int dy = 0; dy < 5; ++dy) {
            const int yy = y + dy - 2;
            if (yy < 0 || yy >= 64) continue;
            #pragma unroll
            for (int dx = 0; dx < 5; ++dx) {
                const int xx = x + dx - 2;
                if (xx < 0 || xx >= 64) continue;
                acc += vb[cbase + (size_t)(yy * 64 + xx) * CC] * wr[dy * 5 + dx];
            }
        }
        xq[cbase + (size_t)(y * 64 + x) * CC] += acc;
    }
}

extern "C" void kernel_launch(void* const* d_in, const int* in_sizes, int n_in,
                              void* d_out, int out_size, void* d_ws, size_t ws_size,
                              hipStream_t stream) {
    (void)in_sizes; (void)n_in; (void)out_size; (void)ws_size;
    const float* x1    = (const float*)d_in[0];
    const float* x2    = (const float*)d_in[1];
    const float* Wq    = (const float*)d_in[2];
    const float* Wkv   = (const float*)d_in[3];
    const float* Wproj = (const float*)d_in[4];
    const float* bproj = (const float*)d_in[5];
    const float* dwcw  = (const float*)d_in[6];
    const float* dwcb  = (const float*)d_in[7];
    const float* scale = (const float*)d_in[8];
    const float* pos   = (const float*)d_in[9];
    float* out = (float*)d_out;

    float* ws = (float*)d_ws;
    const size_t MC = (size_t)CM * CC;
    float* qbuf = ws;                                            // MC
    float* vbuf = ws + MC;                                       // MC
    float* kv2p = ws + 2 * MC;                                   // 40*8*16384 f32
    unsigned short* kv2bf = (unsigned short*)(kv2p + (size_t)40 * NCH * 16384); // 40*16384 u16
    float* ksmp = (float*)(kv2bf + (size_t)40 * 16384);          // 40*8*128 f32
    float* ksm  = ksmp + (size_t)40 * NCH * 128;                 // 40*128
    float* scb  = ksm  + (size_t)40 * 128;                       // 640
    float* kbuf = out;   // k lives in d_out until the final GEMM overwrites it

    hipLaunchKernelGGL(softplus_k, dim3(1), dim3(640), 0, stream, scale, scb);
    hipLaunchKernelGGL((gemm_bf16<false>), dim3(CC/128, CM/128), dim3(256), 0, stream,
                       x2, Wq, vbuf, (const float*)nullptr, CC, CC);
    hipLaunchKernelGGL((gemm_bf16<false>), dim3(CC/128, CM/128), dim3(256), 0, stream,
                       x1, Wkv, kbuf, (const float*)nullptr, CC, CC);
    hipLaunchKernelGGL((gemm_bf16<false>), dim3(CC/128, CM/128), dim3(256), 0, stream,
                       x1, Wkv + (size_t)CC * CC, qbuf, (const float*)nullptr, CC, CC);
    hipLaunchKernelGGL(rowtrans, dim3(CM), dim3(256), 0, stream, qbuf, kbuf, pos, scb);
    hipLaunchKernelGGL(kv2_partial, dim3(NCH, 40), dim3(256), 0, stream, kbuf, vbuf, kv2p, ksmp);
    hipLaunchKernelGGL(kv2_reduce, dim3(40), dim3(256), 0, stream, kv2p, ksmp, kv2bf, ksm);
    hipLaunchKernelGGL(attn_mfma, dim3(CN/128, 40), dim3(256), 0, stream, qbuf, kv2bf, ksm);
    hipLaunchKernelGGL(dwconv_add, dim3(64, 40), dim3(256), 0, stream, vbuf, dwcw, dwcb, qbuf);
    hipLaunchKernelGGL((gemm_bf16<true>), dim3(CC/128, CM/128), dim3(256), 0, stream,
                       qbuf, Wproj, out, bproj, CC, CC);
}

// Round 7
// 595.230 us; speedup vs baseline: 3.4920x; 1.4421x over previous
//
#include <hip/hip_runtime.h>
#include <math.h>

constexpr int CB  = 8;       // batch
constexpr int CN  = 4096;    // tokens
constexpr int CC  = 640;     // channels
constexpr int CNH = 5;       // heads
constexpr int CHD = 128;     // head dim
constexpr int CM  = CB * CN; // 32768 rows
constexpr float CEPS = 1e-6f;
constexpr int NCH = 8;       // n-chunks for kv2 partials

typedef __attribute__((ext_vector_type(8))) short bf16x8;
typedef __attribute__((ext_vector_type(4))) float f32x4;

typedef __attribute__((address_space(1))) const unsigned int gas_u32;
typedef __attribute__((address_space(3))) unsigned int las_u32;

__device__ __forceinline__ void gload16(const void* g, void* l) {
    __builtin_amdgcn_global_load_lds((gas_u32*)g, (las_u32*)l, 16, 0, 0);
}

__device__ __forceinline__ short f2bf(float x) {
    unsigned u = __float_as_uint(x);
    unsigned r = (u + 0x7fffu + ((u >> 16) & 1u)) >> 16;   // RNE, finite data
    return (short)r;
}
__device__ __forceinline__ float b2f(unsigned short u) {
    return __uint_as_float(((unsigned)u) << 16);
}

// ---------------- softplus of scale ----------------
__global__ void softplus_k(const float* __restrict__ scale, float* __restrict__ sc) {
    int t = threadIdx.x;
    if (t < CC) sc[t] = log1pf(expf(scale[t]));
}

// ---------------- f32 -> bf16 cvt, 8 elems/thread grid-stride ----------------
__global__ __launch_bounds__(256) void cvt_bf16(const float* __restrict__ src,
                                                unsigned short* __restrict__ dst, int n8) {
    int i = blockIdx.x * 256 + threadIdx.x;
    const int stride = gridDim.x * 256;
    for (; i < n8; i += stride) {
        float4 f0 = *(const float4*)(src + (size_t)i * 8);
        float4 f1 = *(const float4*)(src + (size_t)i * 8 + 4);
        bf16x8 h;
        h[0]=f2bf(f0.x); h[1]=f2bf(f0.y); h[2]=f2bf(f0.z); h[3]=f2bf(f0.w);
        h[4]=f2bf(f1.x); h[5]=f2bf(f1.y); h[6]=f2bf(f1.z); h[7]=f2bf(f1.w);
        *(bf16x8*)(dst + (size_t)i * 8) = h;
    }
}

// ------- bf16 MFMA GEMM: C[M,N] = A[M,K]*B[N,K]^T (+bias), bf16 in, bf16/f32 out -------
// 128x128 tile, BK=32, 4 waves. global_load_lds(16B) with PRE-SWIZZLED per-lane source:
// LDS chunk c' holds global chunk s = c' ^ (((c'>>2)&7) ^ ((c'>>4)&1)), the inverse of
// the verified read-side swizzle byte ^= ((row&7)<<4) (chunk' = chunk ^ ((chunk>>2)&7)).
template<bool BIAS, bool OUTBF>
__global__ __launch_bounds__(256) void gemm_bf16b(const unsigned short* __restrict__ Abf,
                                                  const unsigned short* __restrict__ Bbf,
                                                  void* __restrict__ Co,
                                                  const float* __restrict__ bias,
                                                  int Kr, int Nr) {
    __shared__ unsigned short lA[4096];   // 128 rows x 32 k, bf16, swizzled
    __shared__ unsigned short lB[4096];
    const int t  = threadIdx.x;
    const int m0 = blockIdx.y * 128;
    const int n0 = blockIdx.x * 128;
    const int l  = t & 63, w = t >> 6, wr = w >> 1, wc = w & 1;

    // per-lane source chunks for the 2 gload calls (chunk = 16B = 8 bf16)
    const int cp0 = w * 64 + l;
    const int cp1 = cp0 + 256;
    const int s0 = cp0 ^ (((cp0 >> 2) & 7) ^ ((cp0 >> 4) & 1));
    const int s1 = cp1 ^ (((cp1 >> 2) & 7) ^ ((cp1 >> 4) & 1));
    const size_t gA0 = (size_t)(m0 + (s0 >> 2)) * Kr + (s0 & 3) * 8;
    const size_t gA1 = (size_t)(m0 + (s1 >> 2)) * Kr + (s1 & 3) * 8;
    const size_t gB0 = (size_t)(n0 + (s0 >> 2)) * Kr + (s0 & 3) * 8;
    const size_t gB1 = (size_t)(n0 + (s1 >> 2)) * Kr + (s1 & 3) * 8;
    unsigned short* lA0 = lA + w * 512;          // wave base, call 0
    unsigned short* lA1 = lA + 2048 + w * 512;   // call 1
    unsigned short* lB0 = lB + w * 512;
    unsigned short* lB1 = lB + 2048 + w * 512;

    const int offA = ((wr * 64 + (l & 15)) * 64 + (l >> 4) * 16) ^ ((l & 7) << 4);
    const int offB = ((wc * 64 + (l & 15)) * 64 + (l >> 4) * 16) ^ ((l & 7) << 4);

    f32x4 acc[4][4];
    #pragma unroll
    for (int i = 0; i < 4; ++i)
        #pragma unroll
        for (int j = 0; j < 4; ++j) acc[i][j] = (f32x4){0.f, 0.f, 0.f, 0.f};

    for (int k0 = 0; k0 < Kr; k0 += 32) {
        gload16(Abf + gA0 + k0, lA0);
        gload16(Abf + gA1 + k0, lA1);
        gload16(Bbf + gB0 + k0, lB0);
        gload16(Bbf + gB1 + k0, lB1);
        __syncthreads();   // drains vmcnt(0): staged data visible; prev reads done before issue
        bf16x8 af[4], bfv[4];
        #pragma unroll
        for (int i = 0; i < 4; ++i) {
            af[i]  = *(const bf16x8*)((const char*)lA + offA + i * 1024);
            bfv[i] = *(const bf16x8*)((const char*)lB + offB + i * 1024);
        }
        #pragma unroll
        for (int i = 0; i < 4; ++i)
            #pragma unroll
            for (int j = 0; j < 4; ++j)
                acc[i][j] = __builtin_amdgcn_mfma_f32_16x16x32_bf16(af[i], bfv[j], acc[i][j], 0, 0, 0);
        __syncthreads();   // protect LDS before next iteration's gload writes
    }

    #pragma unroll
    for (int j = 0; j < 4; ++j) {
        const int n = n0 + wc * 64 + j * 16 + (l & 15);
        const float bv = BIAS ? bias[n] : 0.f;
        #pragma unroll
        for (int i = 0; i < 4; ++i) {
            const int m = m0 + wr * 64 + i * 16 + (l >> 4) * 4;
            #pragma unroll
            for (int r = 0; r < 4; ++r) {
                float val = acc[i][j][r] + bv;
                if (OUTBF) ((unsigned short*)Co)[(size_t)(m + r) * Nr + n] = (unsigned short)f2bf(val);
                else       ((float*)Co)[(size_t)(m + r) * Nr + n] = val;
            }
        }
    }
}

// ------- per-row focused transform (bf16 in, bf16 out) -------
__global__ __launch_bounds__(256) void rowtrans2(const unsigned short* __restrict__ qg,
                                                 const unsigned short* __restrict__ kg,
                                                 const float* __restrict__ pos,
                                                 const float* __restrict__ sc,
                                                 unsigned short* __restrict__ qt,
                                                 unsigned short* __restrict__ kt) {
    const int m = blockIdx.x;
    const int n = m & (CN - 1);
    const int t = threadIdx.x;
    float qv[3], kv[3];
    float s2q = 0.f, s6q = 0.f, s2k = 0.f, s6k = 0.f;
    #pragma unroll
    for (int i = 0; i < 3; ++i) {
        int c = t + i * 256;
        if (c < CC) {
            float scv = sc[c];
            float qq = b2f(qg[(size_t)m * CC + c]);
            qq = (fmaxf(qq, 0.f) + CEPS) / scv;
            float kk = b2f(kg[(size_t)m * CC + c]) + pos[(size_t)n * CC + c];
            kk = (fmaxf(kk, 0.f) + CEPS) / scv;
            qv[i] = qq; kv[i] = kk;
            float q2 = qq * qq, k2 = kk * kk;
            s2q += q2; s6q += q2 * q2 * q2;
            s2k += k2; s6k += k2 * k2 * k2;
        } else { qv[i] = 0.f; kv[i] = 0.f; }
    }
    #pragma unroll
    for (int o = 32; o > 0; o >>= 1) {
        s2q += __shfl_down(s2q, o);
        s6q += __shfl_down(s6q, o);
        s2k += __shfl_down(s2k, o);
        s6k += __shfl_down(s6k, o);
    }
    __shared__ float red[4][4];
    const int lane = t & 63, w = t >> 6;
    if (lane == 0) { red[0][w] = s2q; red[1][w] = s6q; red[2][w] = s2k; red[3][w] = s6k; }
    __syncthreads();
    float t2q = red[0][0] + red[0][1] + red[0][2] + red[0][3];
    float t6q = red[1][0] + red[1][1] + red[1][2] + red[1][3];
    float t2k = red[2][0] + red[2][1] + red[2][2] + red[2][3];
    float t6k = red[3][0] + red[3][1] + red[3][2] + red[3][3];
    const float qmul = sqrtf(t2q) / sqrtf(t6q);
    const float kmul = sqrtf(t2k) / sqrtf(t6k);
    #pragma unroll
    for (int i = 0; i < 3; ++i) {
        int c = t + i * 256;
        if (c < CC) {
            qt[(size_t)m * CC + c] = (unsigned short)f2bf(qv[i] * qv[i] * qv[i] * qmul);
            kt[(size_t)m * CC + c] = (unsigned short)f2bf(kv[i] * kv[i] * kv[i] * kmul);
        }
    }
}

// ------- kv2 partials (bf16 in): per (bh, chunk): K^T V over 512 rows; ksum partial -------
__global__ __launch_bounds__(256) void kv2_partial(const unsigned short* __restrict__ kt,
                                                   const unsigned short* __restrict__ vb,
                                                   float* __restrict__ kv2p,
                                                   float* __restrict__ ksmp) {
    const int nc = blockIdx.x, bh = blockIdx.y;
    const int b = bh / CNH, h = bh % CNH;
    __shared__ float ks[32][132];
    __shared__ float vs[32][132];
    const int t = threadIdx.x;
    const int tx = t & 15, ty = t >> 4;
    float acc[8][8];
    #pragma unroll
    for (int i = 0; i < 8; ++i)
        #pragma unroll
        for (int j = 0; j < 8; ++j) acc[i][j] = 0.f;
    float ksacc = 0.f;
    const size_t mbase = (size_t)b * CN + (size_t)nc * 512;
    for (int tile = 0; tile < 16; ++tile) {
        const int nt0 = tile * 32;
        __syncthreads();
        #pragma unroll
        for (int r = 0; r < 2; ++r) {
            int idx = t + 256 * r;           // < 512
            int nn = idx >> 4, c8 = (idx & 15) * 8;
            size_t g = (mbase + nt0 + nn) * CC + h * CHD + c8;
            bf16x8 hk = *(const bf16x8*)(kt + g);
            bf16x8 hv = *(const bf16x8*)(vb + g);
            float4 k0, k1, v0, v1;
            k0.x=b2f(hk[0]); k0.y=b2f(hk[1]); k0.z=b2f(hk[2]); k0.w=b2f(hk[3]);
            k1.x=b2f(hk[4]); k1.y=b2f(hk[5]); k1.z=b2f(hk[6]); k1.w=b2f(hk[7]);
            v0.x=b2f(hv[0]); v0.y=b2f(hv[1]); v0.z=b2f(hv[2]); v0.w=b2f(hv[3]);
            v1.x=b2f(hv[4]); v1.y=b2f(hv[5]); v1.z=b2f(hv[6]); v1.w=b2f(hv[7]);
            *(float4*)&ks[nn][c8]     = k0;
            *(float4*)&ks[nn][c8 + 4] = k1;
            *(float4*)&vs[nn][c8]     = v0;
            *(float4*)&vs[nn][c8 + 4] = v1;
        }
        __syncthreads();
        #pragma unroll 2
        for (int nn = 0; nn < 32; ++nn) {
            float4 a0 = *(const float4*)&ks[nn][ty*8];
            float4 a1 = *(const float4*)&ks[nn][ty*8+4];
            float4 b0 = *(const float4*)&vs[nn][tx*8];
            float4 b1 = *(const float4*)&vs[nn][tx*8+4];
            float a[8] = {a0.x,a0.y,a0.z,a0.w,a1.x,a1.y,a1.z,a1.w};
            float b[8] = {b0.x,b0.y,b0.z,b0.w,b1.x,b1.y,b1.z,b1.w};
            #pragma unroll
            for (int i = 0; i < 8; ++i)
                #pragma unroll
                for (int j = 0; j < 8; ++j)
                    acc[i][j] = fmaf(a[i], b[j], acc[i][j]);
        }
        if (t < 128) {
            #pragma unroll
            for (int nn = 0; nn < 32; ++nn) ksacc += ks[nn][t];
        }
    }
    float* outp = kv2p + ((size_t)bh * NCH + nc) * 16384;
    #pragma unroll
    for (int i = 0; i < 8; ++i) {
        float4 o0, o1;
        o0.x=acc[i][0]; o0.y=acc[i][1]; o0.z=acc[i][2]; o0.w=acc[i][3];
        o1.x=acc[i][4]; o1.y=acc[i][5]; o1.z=acc[i][6]; o1.w=acc[i][7];
        *(float4*)&outp[(ty*8+i)*128 + tx*8]     = o0;
        *(float4*)&outp[(ty*8+i)*128 + tx*8 + 4] = o1;
    }
    if (t < 128) ksmp[((size_t)bh * NCH + nc) * 128 + t] = ksacc;
}

// ------- reduce partials; emit kv2^T as bf16 [d][c] + ksum f32 -------
__global__ __launch_bounds__(256) void kv2_reduce(const float* __restrict__ kv2p,
                                                  const float* __restrict__ ksmp,
                                                  unsigned short* __restrict__ kv2bf,
                                                  float* __restrict__ ksm) {
    const int bh = blockIdx.x, t = threadIdx.x;
    for (int o = t; o < 16384; o += 256) {
        const int d = o >> 7, c = o & 127;
        float s = 0.f;
        #pragma unroll
        for (int nc = 0; nc < NCH; ++nc)
            s += kv2p[((size_t)bh * NCH + nc) * 16384 + c * 128 + d];
        kv2bf[(size_t)bh * 16384 + o] = (unsigned short)f2bf(s);
    }
    if (t < 128) {
        float s = 0.f;
        #pragma unroll
        for (int nc = 0; nc < NCH; ++nc) s += ksmp[((size_t)bh * NCH + nc) * 128 + t];
        ksm[(size_t)bh * 128 + t] = s;
    }
}

// ------- attention out via MFMA: att = (q@kv2)*z, bf16 in/out -------
__global__ __launch_bounds__(256) void attn_mfma(const unsigned short* __restrict__ qt,
                                                 const unsigned short* __restrict__ kv2bf,
                                                 const float* __restrict__ ksm,
                                                 unsigned short* __restrict__ attb) {
    const int nb = blockIdx.x, bh = blockIdx.y;
    const int b = bh / CNH, h = bh % CNH;
    __shared__ short lQ[16384];    // 128 x 128 bf16, swizzled
    __shared__ short lKV[16384];   // [d][c] bf16, swizzled
    __shared__ float zs[128];
    const int t = threadIdx.x;
    const int l = t & 63, w = t >> 6, wr = w >> 1, wc = w & 1;
    const size_t m0 = (size_t)b * CN + (size_t)nb * 128;

    const int srow0 = t >> 4;      // 0..15
    const int c16   = t & 15;      // 16B chunk within row
    float kreg[8];
    {
        const float* kp = ksm + (size_t)bh * 128 + c16 * 8;
        float4 k0 = *(const float4*)kp, k1 = *(const float4*)(kp + 4);
        kreg[0]=k0.x; kreg[1]=k0.y; kreg[2]=k0.z; kreg[3]=k0.w;
        kreg[4]=k1.x; kreg[5]=k1.y; kreg[6]=k1.z; kreg[7]=k1.w;
    }
    #pragma unroll
    for (int p = 0; p < 8; ++p) {
        const int row = srow0 + p * 16;
        const int st = (row * 256 + c16 * 16) ^ ((row & 7) << 4);
        bf16x8 hq = *(const bf16x8*)(qt + (m0 + row) * CC + h * CHD + c16 * 8);
        *(bf16x8*)((char*)lQ + st) = hq;
        float zp = 0.f;
        #pragma unroll
        for (int j = 0; j < 8; ++j) zp = fmaf(b2f((unsigned short)hq[j]), kreg[j], zp);
        zp += __shfl_xor(zp, 1);
        zp += __shfl_xor(zp, 2);
        zp += __shfl_xor(zp, 4);
        zp += __shfl_xor(zp, 8);
        if (c16 == 0) zs[row] = 1.f / (zp + CEPS);
        bf16x8 hk = *(const bf16x8*)(kv2bf + (size_t)bh * 16384 + row * 128 + c16 * 8);
        *(bf16x8*)((char*)lKV + st) = hk;
    }
    __syncthreads();

    const int baseA = (wr * 64 + (l & 15)) * 256 + ((l >> 4) << 4);
    const int baseB = (wc * 64 + (l & 15)) * 256 + ((l >> 4) << 4);
    const int xorv  = (l & 7) << 4;
    f32x4 acc[4][4];
    #pragma unroll
    for (int i = 0; i < 4; ++i)
        #pragma unroll
        for (int j = 0; j < 4; ++j) acc[i][j] = (f32x4){0.f, 0.f, 0.f, 0.f};

    #pragma unroll
    for (int kk = 0; kk < 4; ++kk) {
        bf16x8 af[4], bv[4];
        #pragma unroll
        for (int i = 0; i < 4; ++i) {
            af[i] = *(const bf16x8*)((const char*)lQ  + (((baseA + kk * 64) ^ xorv) + i * 4096));
            bv[i] = *(const bf16x8*)((const char*)lKV + (((baseB + kk * 64) ^ xorv) + i * 4096));
        }
        #pragma unroll
        for (int i = 0; i < 4; ++i)
            #pragma unroll
            for (int j = 0; j < 4; ++j)
                acc[i][j] = __builtin_amdgcn_mfma_f32_16x16x32_bf16(af[i], bv[j], acc[i][j], 0, 0, 0);
    }

    #pragma unroll
    for (int i = 0; i < 4; ++i) {
        const int mBase = wr * 64 + i * 16 + (l >> 4) * 4;
        float zv[4];
        #pragma unroll
        for (int r = 0; r < 4; ++r) zv[r] = zs[mBase + r];
        #pragma unroll
        for (int j = 0; j < 4; ++j) {
            const int n = wc * 64 + j * 16 + (l & 15);
            unsigned short* op = attb + (m0 + mBase) * CC + h * CHD + n;
            #pragma unroll
            for (int r = 0; r < 4; ++r)
                op[(size_t)r * CC] = (unsigned short)f2bf(acc[i][j][r] * zv[r]);
        }
    }
}

// ------- LDS-tiled 5x5 depthwise conv: x = att + conv(v) + bias, bf16 in/out -------
// block = (y-tile of 8 rows, d-quarter of 32 ch, bh). LDS: 12x68x32 bf16 halo'd tile.
// NOTE: dwc_w is (HD,1,5,5) — indexed by head-dim channel d0 ONLY (shared across heads).
__global__ __launch_bounds__(256) void dwconv2(const unsigned short* __restrict__ vb,
                                               const unsigned short* __restrict__ attb,
                                               const float* __restrict__ w,
                                               const float* __restrict__ bias,
                                               unsigned short* __restrict__ xb) {
    const int yt = blockIdx.x;      // 0..7
    const int dq = blockIdx.y;      // 0..3
    const int bh = blockIdx.z;      // 0..39
    const int b = bh / CNH, h = bh % CNH;
    __shared__ unsigned short vt[12 * 68 * 32];
    const int t = threadIdx.x;
    const int y0 = yt * 8;
    const size_t rowbase = (size_t)b * CN;
    const int cbase = h * CHD + dq * 32;
    // stage halo'd tile (zero-padded)
    for (int c = t; c < 3264; c += 256) {
        int pos = c >> 2, d8 = (c & 3) * 8;
        int ly = pos / 68, lx = pos - ly * 68;
        int yy = y0 - 2 + ly, xx = lx - 2;
        bf16x8 val = (bf16x8){0,0,0,0,0,0,0,0};
        if (yy >= 0 && yy < 64 && xx >= 0 && xx < 64)
            val = *(const bf16x8*)(vb + (rowbase + yy * 64 + xx) * CC + cbase + d8);
        *(bf16x8*)(vt + pos * 32 + d8) = val;
    }
    __syncthreads();
    const int dp = t & 15;          // channel pair idx
    const int xg = t >> 4;          // 0..15, 4 x-positions each
    const int d0 = dq * 32 + dp * 2;            // head-dim channel in [0,128)
    float wr0[25], wr1[25];
    #pragma unroll
    for (int i = 0; i < 25; ++i) {
        wr0[i] = w[d0 * 25 + i];                // FIXED: weight indexed by d0 only
        wr1[i] = w[(d0 + 1) * 25 + i];
    }
    const float bv0 = bias[d0], bv1 = bias[d0 + 1];   // FIXED: bias indexed by d0 only
    const int x0 = xg * 4;
    for (int oy = 0; oy < 8; ++oy) {
        float a0[4] = {bv0, bv0, bv0, bv0}, a1[4] = {bv1, bv1, bv1, bv1};
        #pragma unroll
        for (int dy = 0; dy < 5; ++dy) {
            const unsigned short* rp = vt + ((oy + dy) * 68 + x0) * 32 + dp * 2;
            float v0[8], v1[8];
            #pragma unroll
            for (int j = 0; j < 8; ++j) {
                unsigned pr = *(const unsigned*)(rp + j * 32);
                v0[j] = __uint_as_float(pr << 16);
                v1[j] = __uint_as_float(pr & 0xffff0000u);
            }
            #pragma unroll
            for (int dx = 0; dx < 5; ++dx) {
                const float w0 = wr0[dy * 5 + dx], w1 = wr1[dy * 5 + dx];
                #pragma unroll
                for (int xo = 0; xo < 4; ++xo) {
                    a0[xo] = fmaf(w0, v0[xo + dx], a0[xo]);
                    a1[xo] = fmaf(w1, v1[xo + dx], a1[xo]);
                }
            }
        }
        #pragma unroll
        for (int xo = 0; xo < 4; ++xo) {
            size_t g = (rowbase + (y0 + oy) * 64 + x0 + xo) * CC + cbase + dp * 2;
            unsigned ap = *(const unsigned*)(attb + g);
            float at0 = __uint_as_float(ap << 16);
            float at1 = __uint_as_float(ap & 0xffff0000u);
            unsigned short o0 = (unsigned short)f2bf(a0[xo] + at0);
            unsigned short o1 = (unsigned short)f2bf(a1[xo] + at1);
            *(unsigned*)(xb + g) = (unsigned)o0 | ((unsigned)o1 << 16);
        }
    }
}

extern "C" void kernel_launch(void* const* d_in, const int* in_sizes, int n_in,
                              void* d_out, int out_size, void* d_ws, size_t ws_size,
                              hipStream_t stream) {
    (void)in_sizes; (void)n_in; (void)out_size; (void)ws_size;
    const float* x1    = (const float*)d_in[0];
    const float* x2    = (const float*)d_in[1];
    const float* Wq    = (const float*)d_in[2];
    const float* Wkv   = (const float*)d_in[3];
    const float* Wproj = (const float*)d_in[4];
    const float* bproj = (const float*)d_in[5];
    const float* dwcw  = (const float*)d_in[6];
    const float* dwcb  = (const float*)d_in[7];
    const float* scale = (const float*)d_in[8];
    const float* pos   = (const float*)d_in[9];
    float* out = (float*)d_out;

    const size_t MC = (size_t)CM * CC;   // 20,971,520 elems
    unsigned short* ws16 = (unsigned short*)d_ws;
    // region A [0, MC): x1bf -> kv2p(f32, first half) -> attbf
    unsigned short* x1bf  = ws16;
    float*          kv2p  = (float*)ws16;                 // 40*8*16384 f32 = 21MB (fits in A)
    unsigned short* attbf = ws16;
    // region B [MC, 2MC): x2bf -> qgbf -> xbf
    unsigned short* x2bf = ws16 + MC;
    unsigned short* qgbf = x2bf;
    unsigned short* xbf  = x2bf;
    // region C [2MC, 3MC): vbf
    unsigned short* vbf  = ws16 + 2 * MC;
    // region D [3MC, 4MC): qtbf
    unsigned short* qtbf = ws16 + 3 * MC;
    // tail
    unsigned short* kv2bf = ws16 + 4 * MC;                          // 40*16384 bf16
    float* ksmp = (float*)(kv2bf + (size_t)40 * 16384);             // 40*8*128 f32
    float* ksm  = ksmp + (size_t)40 * NCH * 128;                    // 40*128
    float* scb  = ksm + (size_t)40 * 128;                           // 640
    unsigned short* Wqbf    = (unsigned short*)(scb + 640);         // 640*640
    unsigned short* Wkvbf   = Wqbf + (size_t)CC * CC;               // 1280*640
    unsigned short* Wprojbf = Wkvbf + (size_t)2 * CC * CC;          // 640*640
    // k path lives in d_out: kgbf (gemm out) in first half, ktbf (focused) in second
    unsigned short* kgbf = (unsigned short*)d_out;
    unsigned short* ktbf = kgbf + MC;

    hipLaunchKernelGGL(softplus_k, dim3(1), dim3(640), 0, stream, scale, scb);
    hipLaunchKernelGGL(cvt_bf16, dim3(2048), dim3(256), 0, stream, x1, x1bf, (int)(MC / 8));
    hipLaunchKernelGGL(cvt_bf16, dim3(2048), dim3(256), 0, stream, x2, x2bf, (int)(MC / 8));
    hipLaunchKernelGGL(cvt_bf16, dim3(64),  dim3(256), 0, stream, Wq,    Wqbf,    CC * CC / 8);
    hipLaunchKernelGGL(cvt_bf16, dim3(128), dim3(256), 0, stream, Wkv,   Wkvbf,   2 * CC * CC / 8);
    hipLaunchKernelGGL(cvt_bf16, dim3(64),  dim3(256), 0, stream, Wproj, Wprojbf, CC * CC / 8);

    hipLaunchKernelGGL((gemm_bf16b<false, true>), dim3(CC/128, CM/128), dim3(256), 0, stream,
                       x2bf, Wqbf, (void*)vbf, (const float*)nullptr, CC, CC);
    hipLaunchKernelGGL((gemm_bf16b<false, true>), dim3(CC/128, CM/128), dim3(256), 0, stream,
                       x1bf, Wkvbf, (void*)kgbf, (const float*)nullptr, CC, CC);
    hipLaunchKernelGGL((gemm_bf16b<false, true>), dim3(CC/128, CM/128), dim3(256), 0, stream,
                       x1bf, Wkvbf + (size_t)CC * CC, (void*)qgbf, (const float*)nullptr, CC, CC);
    hipLaunchKernelGGL(rowtrans2, dim3(CM), dim3(256), 0, stream, qgbf, kgbf, pos, scb, qtbf, ktbf);
    hipLaunchKernelGGL(kv2_partial, dim3(NCH, 40), dim3(256), 0, stream, ktbf, vbf, kv2p, ksmp);
    hipLaunchKernelGGL(kv2_reduce, dim3(40), dim3(256), 0, stream, kv2p, ksmp, kv2bf, ksm);
    hipLaunchKernelGGL(attn_mfma, dim3(CN/128, 40), dim3(256), 0, stream, qtbf, kv2bf, ksm, attbf);
    hipLaunchKernelGGL(dwconv2, dim3(8, 4, 40), dim3(256), 0, stream, vbf, attbf, dwcw, dwcb, xbf);
    hipLaunchKernelGGL((gemm_bf16b<true, false>), dim3(CC/128, CM/128), dim3(256), 0, stream,
                       xbf, Wprojbf, (void*)out, bproj, CC, CC);
}

// Round 8
// 536.232 us; speedup vs baseline: 3.8762x; 1.1100x over previous
//
#include <hip/hip_runtime.h>
#include <math.h>

constexpr int CB  = 8;       // batch
constexpr int CN  = 4096;    // tokens
constexpr int CC  = 640;     // channels
constexpr int CNH = 5;       // heads
constexpr int CHD = 128;     // head dim
constexpr int CM  = CB * CN; // 32768 rows
constexpr float CEPS = 1e-6f;
constexpr int NCH = 8;       // token chunks for kv2 partials

typedef __attribute__((ext_vector_type(8))) short bf16x8;
typedef __attribute__((ext_vector_type(4))) float f32x4;

typedef __attribute__((address_space(1))) const unsigned int gas_u32;
typedef __attribute__((address_space(3))) unsigned int las_u32;

__device__ __forceinline__ void gload16(const void* g, void* l) {
    __builtin_amdgcn_global_load_lds((gas_u32*)g, (las_u32*)l, 16, 0, 0);
}

__device__ __forceinline__ short f2bf(float x) {
    unsigned u = __float_as_uint(x);
    unsigned r = (u + 0x7fffu + ((u >> 16) & 1u)) >> 16;   // RNE, finite data
    return (short)r;
}
__device__ __forceinline__ float b2f(unsigned short u) {
    return __uint_as_float(((unsigned)u) << 16);
}

// ---------------- softplus of scale ----------------
__global__ void softplus_k(const float* __restrict__ scale, float* __restrict__ sc) {
    int t = threadIdx.x;
    if (t < CC) sc[t] = log1pf(expf(scale[t]));
}

// ---------------- f32 -> bf16 cvt, 8 elems/thread grid-stride ----------------
__global__ __launch_bounds__(256) void cvt_bf16(const float* __restrict__ src,
                                                unsigned short* __restrict__ dst, int n8) {
    int i = blockIdx.x * 256 + threadIdx.x;
    const int stride = gridDim.x * 256;
    for (; i < n8; i += stride) {
        float4 f0 = *(const float4*)(src + (size_t)i * 8);
        float4 f1 = *(const float4*)(src + (size_t)i * 8 + 4);
        bf16x8 h;
        h[0]=f2bf(f0.x); h[1]=f2bf(f0.y); h[2]=f2bf(f0.z); h[3]=f2bf(f0.w);
        h[4]=f2bf(f1.x); h[5]=f2bf(f1.y); h[6]=f2bf(f1.z); h[7]=f2bf(f1.w);
        *(bf16x8*)(dst + (size_t)i * 8) = h;
    }
}

// ------- bf16 MFMA GEMM: C[M,N] = A[M,K]*B[N,K]^T (+bias), bf16 in, bf16/f32 out -------
// 128x128 tile, BK=32, 4 waves, DOUBLE-BUFFERED LDS (one barrier/K-step; stage next
// tile into buf^1 before computing buf). global_load_lds(16B), pre-swizzled source.
template<bool BIAS, bool OUTBF>
__global__ __launch_bounds__(256) void gemm_bf16b(const unsigned short* __restrict__ Abf,
                                                  const unsigned short* __restrict__ Bbf,
                                                  void* __restrict__ Co,
                                                  const float* __restrict__ bias,
                                                  int Kr, int Nr) {
    __shared__ unsigned short lA[2][4096];
    __shared__ unsigned short lB[2][4096];
    const int t  = threadIdx.x;
    const int m0 = blockIdx.y * 128;
    const int n0 = blockIdx.x * 128;
    const int l  = t & 63, w = t >> 6, wr = w >> 1, wc = w & 1;

    // per-lane source chunks (chunk = 16B = 8 bf16); inverse of read-side XOR
    const int cp0 = w * 64 + l;
    const int cp1 = cp0 + 256;
    const int s0 = cp0 ^ (((cp0 >> 2) & 7) ^ ((cp0 >> 4) & 1));
    const int s1 = cp1 ^ (((cp1 >> 2) & 7) ^ ((cp1 >> 4) & 1));
    const size_t gA0 = (size_t)(m0 + (s0 >> 2)) * Kr + (s0 & 3) * 8;
    const size_t gA1 = (size_t)(m0 + (s1 >> 2)) * Kr + (s1 & 3) * 8;
    const size_t gB0 = (size_t)(n0 + (s0 >> 2)) * Kr + (s0 & 3) * 8;
    const size_t gB1 = (size_t)(n0 + (s1 >> 2)) * Kr + (s1 & 3) * 8;
    const int dA0 = w * 512;          // LDS elem offset, call 0
    const int dA1 = 2048 + w * 512;   // call 1

    const int offA = ((wr * 64 + (l & 15)) * 64 + (l >> 4) * 16) ^ ((l & 7) << 4);
    const int offB = ((wc * 64 + (l & 15)) * 64 + (l >> 4) * 16) ^ ((l & 7) << 4);

    f32x4 acc[4][4];
    #pragma unroll
    for (int i = 0; i < 4; ++i)
        #pragma unroll
        for (int j = 0; j < 4; ++j) acc[i][j] = (f32x4){0.f, 0.f, 0.f, 0.f};

    // prologue: stage tile 0 into buf 0
    gload16(Abf + gA0, &lA[0][dA0]);
    gload16(Abf + gA1, &lA[0][dA1]);
    gload16(Bbf + gB0, &lB[0][dA0]);
    gload16(Bbf + gB1, &lB[0][dA1]);
    __syncthreads();

    int cur = 0;
    for (int k0 = 0; k0 < Kr; k0 += 32) {
        if (k0 + 32 < Kr) {   // stage next tile into the other buffer
            const int nb = cur ^ 1;
            gload16(Abf + gA0 + k0 + 32, &lA[nb][dA0]);
            gload16(Abf + gA1 + k0 + 32, &lA[nb][dA1]);
            gload16(Bbf + gB0 + k0 + 32, &lB[nb][dA0]);
            gload16(Bbf + gB1 + k0 + 32, &lB[nb][dA1]);
        }
        bf16x8 af[4], bfv[4];
        #pragma unroll
        for (int i = 0; i < 4; ++i) {
            af[i]  = *(const bf16x8*)((const char*)&lA[cur][0] + offA + i * 1024);
            bfv[i] = *(const bf16x8*)((const char*)&lB[cur][0] + offB + i * 1024);
        }
        #pragma unroll
        for (int i = 0; i < 4; ++i)
            #pragma unroll
            for (int j = 0; j < 4; ++j)
                acc[i][j] = __builtin_amdgcn_mfma_f32_16x16x32_bf16(af[i], bfv[j], acc[i][j], 0, 0, 0);
        __syncthreads();   // drains vmcnt(0): next buf staged; all reads of cur done
        cur ^= 1;
    }

    #pragma unroll
    for (int j = 0; j < 4; ++j) {
        const int n = n0 + wc * 64 + j * 16 + (l & 15);
        const float bv = BIAS ? bias[n] : 0.f;
        #pragma unroll
        for (int i = 0; i < 4; ++i) {
            const int m = m0 + wr * 64 + i * 16 + (l >> 4) * 4;
            #pragma unroll
            for (int r = 0; r < 4; ++r) {
                float val = acc[i][j][r] + bv;
                if (OUTBF) ((unsigned short*)Co)[(size_t)(m + r) * Nr + n] = (unsigned short)f2bf(val);
                else       ((float*)Co)[(size_t)(m + r) * Nr + n] = val;
            }
        }
    }
}

// ------- per-row focused transform: one row per WAVE, shfl-only reduce -------
// kq layout: [m][1280], cols 0..639 = k (Wkv rows 0..639), 640..1279 = q.
__global__ __launch_bounds__(256) void rowtrans2(const unsigned short* __restrict__ kq,
                                                 const float* __restrict__ pos,
                                                 const float* __restrict__ sc,
                                                 unsigned short* __restrict__ qt,
                                                 unsigned short* __restrict__ kt) {
    const int w = threadIdx.x >> 6, l = threadIdx.x & 63;
    const int m = blockIdx.x * 4 + w;
    const int n = m & (CN - 1);
    const unsigned short* rowk = kq + (size_t)m * 1280;
    const unsigned short* rowq = rowk + 640;
    float qv[10], kv[10];
    float s2q = 0.f, s6q = 0.f, s2k = 0.f, s6k = 0.f;
    #pragma unroll
    for (int j = 0; j < 10; ++j) {
        const int c = l + 64 * j;
        const float scv = sc[c];
        float qq = (fmaxf(b2f(rowq[c]), 0.f) + CEPS) / scv;
        float kk = (fmaxf(b2f(rowk[c]) + pos[(size_t)n * CC + c], 0.f) + CEPS) / scv;
        qv[j] = qq; kv[j] = kk;
        const float q2 = qq * qq, k2 = kk * kk;
        s2q += q2; s6q += q2 * q2 * q2;
        s2k += k2; s6k += k2 * k2 * k2;
    }
    #pragma unroll
    for (int o = 32; o > 0; o >>= 1) {
        s2q += __shfl_xor(s2q, o);
        s6q += __shfl_xor(s6q, o);
        s2k += __shfl_xor(s2k, o);
        s6k += __shfl_xor(s6k, o);
    }
    const float qmul = sqrtf(s2q) / sqrtf(s6q);
    const float kmul = sqrtf(s2k) / sqrtf(s6k);
    #pragma unroll
    for (int j = 0; j < 10; ++j) {
        const int c = l + 64 * j;
        qt[(size_t)m * CC + c] = (unsigned short)f2bf(qv[j] * qv[j] * qv[j] * qmul);
        kt[(size_t)m * CC + c] = (unsigned short)f2bf(kv[j] * kv[j] * kv[j] * kmul);
    }
}

// ------- kv2 partials, QUADRANT split: per (nc, bh, q): 64x64 of K^T V over 512 rows -------
// q = blockIdx.z: qc = q&1 (c-half of K), qd = q>>1 (d-half of V). 4x4 acc/thread.
__global__ __launch_bounds__(256) void kv2_partial(const unsigned short* __restrict__ kt,
                                                   const unsigned short* __restrict__ vb,
                                                   float* __restrict__ kv2p,
                                                   float* __restrict__ ksmp) {
    const int nc = blockIdx.x, bh = blockIdx.y, q = blockIdx.z;
    const int qc = q & 1, qd = q >> 1;
    const int b = bh / CNH, h = bh % CNH;
    __shared__ float ks[32][68];
    __shared__ float vs[32][68];
    const int t = threadIdx.x;
    const int tx = t & 15, ty = t >> 4;
    float acc[4][4];
    #pragma unroll
    for (int i = 0; i < 4; ++i)
        #pragma unroll
        for (int j = 0; j < 4; ++j) acc[i][j] = 0.f;
    float ksacc = 0.f;
    const size_t mbase = (size_t)b * CN + (size_t)nc * 512;
    const int cofK = h * CHD + qc * 64;
    const int cofV = h * CHD + qd * 64;
    const int token = t >> 3, c8 = (t & 7) * 8;
    for (int tile = 0; tile < 16; ++tile) {
        const int nt0 = tile * 32;
        __syncthreads();
        {
            const size_t r = (mbase + nt0 + token) * CC;
            bf16x8 hk = *(const bf16x8*)(kt + r + cofK + c8);
            bf16x8 hv = *(const bf16x8*)(vb + r + cofV + c8);
            float4 k0, k1, v0, v1;
            k0.x=b2f(hk[0]); k0.y=b2f(hk[1]); k0.z=b2f(hk[2]); k0.w=b2f(hk[3]);
            k1.x=b2f(hk[4]); k1.y=b2f(hk[5]); k1.z=b2f(hk[6]); k1.w=b2f(hk[7]);
            v0.x=b2f(hv[0]); v0.y=b2f(hv[1]); v0.z=b2f(hv[2]); v0.w=b2f(hv[3]);
            v1.x=b2f(hv[4]); v1.y=b2f(hv[5]); v1.z=b2f(hv[6]); v1.w=b2f(hv[7]);
            *(float4*)&ks[token][c8]     = k0;
            *(float4*)&ks[token][c8 + 4] = k1;
            *(float4*)&vs[token][c8]     = v0;
            *(float4*)&vs[token][c8 + 4] = v1;
        }
        __syncthreads();
        #pragma unroll 4
        for (int nn = 0; nn < 32; ++nn) {
            float4 av = *(const float4*)&ks[nn][ty * 4];
            float4 bv = *(const float4*)&vs[nn][tx * 4];
            float a[4] = {av.x, av.y, av.z, av.w};
            float bb[4] = {bv.x, bv.y, bv.z, bv.w};
            #pragma unroll
            for (int i = 0; i < 4; ++i)
                #pragma unroll
                for (int j = 0; j < 4; ++j)
                    acc[i][j] = fmaf(a[i], bb[j], acc[i][j]);
        }
        if (qd == 0 && t < 64) {
            #pragma unroll
            for (int nn = 0; nn < 32; ++nn) ksacc += ks[nn][t];
        }
    }
    float* outp = kv2p + (((size_t)bh * NCH + nc) * 4 + q) * 4096;
    #pragma unroll
    for (int i = 0; i < 4; ++i) {
        float4 o;
        o.x = acc[i][0]; o.y = acc[i][1]; o.z = acc[i][2]; o.w = acc[i][3];
        *(float4*)&outp[(ty * 4 + i) * 64 + tx * 4] = o;
    }
    if (qd == 0 && t < 64)
        ksmp[(((size_t)bh * NCH + nc) * 2 + qc) * 64 + t] = ksacc;
}

// ------- reduce partials; emit kv2^T as bf16 [d][c] + ksum f32 -------
__global__ __launch_bounds__(256) void kv2_reduce(const float* __restrict__ kv2p,
                                                  const float* __restrict__ ksmp,
                                                  unsigned short* __restrict__ kv2bf,
                                                  float* __restrict__ ksm) {
    const int bh = blockIdx.x, t = threadIdx.x;
    for (int o = t; o < 16384; o += 256) {
        const int d = o >> 7, c = o & 127;
        const int q = (d >> 6) * 2 + (c >> 6);
        float s = 0.f;
        #pragma unroll
        for (int nc = 0; nc < NCH; ++nc)
            s += kv2p[(((size_t)bh * NCH + nc) * 4 + q) * 4096 + (c & 63) * 64 + (d & 63)];
        kv2bf[(size_t)bh * 16384 + o] = (unsigned short)f2bf(s);
    }
    if (t < 128) {
        float s = 0.f;
        #pragma unroll
        for (int nc = 0; nc < NCH; ++nc)
            s += ksmp[(((size_t)bh * NCH + nc) * 2 + (t >> 6)) * 64 + (t & 63)];
        ksm[(size_t)bh * 128 + t] = s;
    }
}

// ------- attention out via MFMA: att = (q@kv2)*z, bf16 in/out -------
__global__ __launch_bounds__(256) void attn_mfma(const unsigned short* __restrict__ qt,
                                                 const unsigned short* __restrict__ kv2bf,
                                                 const float* __restrict__ ksm,
                                                 unsigned short* __restrict__ attb) {
    const int nb = blockIdx.x, bh = blockIdx.y;
    const int b = bh / CNH, h = bh % CNH;
    __shared__ short lQ[16384];    // 128 x 128 bf16, swizzled
    __shared__ short lKV[16384];   // [d][c] bf16, swizzled
    __shared__ float zs[128];
    const int t = threadIdx.x;
    const int l = t & 63, w = t >> 6, wr = w >> 1, wc = w & 1;
    const size_t m0 = (size_t)b * CN + (size_t)nb * 128;

    const int srow0 = t >> 4;      // 0..15
    const int c16   = t & 15;      // 16B chunk within row
    float kreg[8];
    {
        const float* kp = ksm + (size_t)bh * 128 + c16 * 8;
        float4 k0 = *(const float4*)kp, k1 = *(const float4*)(kp + 4);
        kreg[0]=k0.x; kreg[1]=k0.y; kreg[2]=k0.z; kreg[3]=k0.w;
        kreg[4]=k1.x; kreg[5]=k1.y; kreg[6]=k1.z; kreg[7]=k1.w;
    }
    #pragma unroll
    for (int p = 0; p < 8; ++p) {
        const int row = srow0 + p * 16;
        const int st = (row * 256 + c16 * 16) ^ ((row & 7) << 4);
        bf16x8 hq = *(const bf16x8*)(qt + (m0 + row) * CC + h * CHD + c16 * 8);
        *(bf16x8*)((char*)lQ + st) = hq;
        float zp = 0.f;
        #pragma unroll
        for (int j = 0; j < 8; ++j) zp = fmaf(b2f((unsigned short)hq[j]), kreg[j], zp);
        zp += __shfl_xor(zp, 1);
        zp += __shfl_xor(zp, 2);
        zp += __shfl_xor(zp, 4);
        zp += __shfl_xor(zp, 8);
        if (c16 == 0) zs[row] = 1.f / (zp + CEPS);
        bf16x8 hk = *(const bf16x8*)(kv2bf + (size_t)bh * 16384 + row * 128 + c16 * 8);
        *(bf16x8*)((char*)lKV + st) = hk;
    }
    __syncthreads();

    const int baseA = (wr * 64 + (l & 15)) * 256 + ((l >> 4) << 4);
    const int baseB = (wc * 64 + (l & 15)) * 256 + ((l >> 4) << 4);
    const int xorv  = (l & 7) << 4;
    f32x4 acc[4][4];
    #pragma unroll
    for (int i = 0; i < 4; ++i)
        #pragma unroll
        for (int j = 0; j < 4; ++j) acc[i][j] = (f32x4){0.f, 0.f, 0.f, 0.f};

    #pragma unroll
    for (int kk = 0; kk < 4; ++kk) {
        bf16x8 af[4], bv[4];
        #pragma unroll
        for (int i = 0; i < 4; ++i) {
            af[i] = *(const bf16x8*)((const char*)lQ  + (((baseA + kk * 64) ^ xorv) + i * 4096));
            bv[i] = *(const bf16x8*)((const char*)lKV + (((baseB + kk * 64) ^ xorv) + i * 4096));
        }
        #pragma unroll
        for (int i = 0; i < 4; ++i)
            #pragma unroll
            for (int j = 0; j < 4; ++j)
                acc[i][j] = __builtin_amdgcn_mfma_f32_16x16x32_bf16(af[i], bv[j], acc[i][j], 0, 0, 0);
    }

    #pragma unroll
    for (int i = 0; i < 4; ++i) {
        const int mBase = wr * 64 + i * 16 + (l >> 4) * 4;
        float zv[4];
        #pragma unroll
        for (int r = 0; r < 4; ++r) zv[r] = zs[mBase + r];
        #pragma unroll
        for (int j = 0; j < 4; ++j) {
            const int n = wc * 64 + j * 16 + (l & 15);
            unsigned short* op = attb + (m0 + mBase) * CC + h * CHD + n;
            #pragma unroll
            for (int r = 0; r < 4; ++r)
                op[(size_t)r * CC] = (unsigned short)f2bf(acc[i][j][r] * zv[r]);
        }
    }
}

// ------- LDS-tiled 5x5 depthwise conv: x = att + conv(v) + bias, bf16 in/out -------
// dwc_w is (HD,1,5,5): indexed by head-dim channel only (shared across heads).
__global__ __launch_bounds__(256) void dwconv2(const unsigned short* __restrict__ vb,
                                               const unsigned short* __restrict__ attb,
                                               const float* __restrict__ w,
                                               const float* __restrict__ bias,
                                               unsigned short* __restrict__ xb) {
    const int yt = blockIdx.x;      // 0..7
    const int dq = blockIdx.y;      // 0..3
    const int bh = blockIdx.z;      // 0..39
    const int b = bh / CNH, h = bh % CNH;
    __shared__ unsigned short vt[12 * 68 * 32];
    const int t = threadIdx.x;
    const int y0 = yt * 8;
    const size_t rowbase = (size_t)b * CN;
    const int cbase = h * CHD + dq * 32;
    for (int c = t; c < 3264; c += 256) {
        int pos = c >> 2, d8 = (c & 3) * 8;
        int ly = pos / 68, lx = pos - ly * 68;
        int yy = y0 - 2 + ly, xx = lx - 2;
        bf16x8 val = (bf16x8){0,0,0,0,0,0,0,0};
        if (yy >= 0 && yy < 64 && xx >= 0 && xx < 64)
            val = *(const bf16x8*)(vb + (rowbase + yy * 64 + xx) * CC + cbase + d8);
        *(bf16x8*)(vt + pos * 32 + d8) = val;
    }
    __syncthreads();
    const int dp = t & 15;
    const int xg = t >> 4;
    const int d0 = dq * 32 + dp * 2;            // head-dim channel in [0,128)
    float wr0[25], wr1[25];
    #pragma unroll
    for (int i = 0; i < 25; ++i) {
        wr0[i] = w[d0 * 25 + i];
        wr1[i] = w[(d0 + 1) * 25 + i];
    }
    const float bv0 = bias[d0], bv1 = bias[d0 + 1];
    const int x0 = xg * 4;
    for (int oy = 0; oy < 8; ++oy) {
        float a0[4] = {bv0, bv0, bv0, bv0}, a1[4] = {bv1, bv1, bv1, bv1};
        #pragma unroll
        for (int dy = 0; dy < 5; ++dy) {
            const unsigned short* rp = vt + ((oy + dy) * 68 + x0) * 32 + dp * 2;
            float v0[8], v1[8];
            #pragma unroll
            for (int j = 0; j < 8; ++j) {
                unsigned pr = *(const unsigned*)(rp + j * 32);
                v0[j] = __uint_as_float(pr << 16);
                v1[j] = __uint_as_float(pr & 0xffff0000u);
            }
            #pragma unroll
            for (int dx = 0; dx < 5; ++dx) {
                const float w0 = wr0[dy * 5 + dx], w1 = wr1[dy * 5 + dx];
                #pragma unroll
                for (int xo = 0; xo < 4; ++xo) {
                    a0[xo] = fmaf(w0, v0[xo + dx], a0[xo]);
                    a1[xo] = fmaf(w1, v1[xo + dx], a1[xo]);
                }
            }
        }
        #pragma unroll
        for (int xo = 0; xo < 4; ++xo) {
            size_t g = (rowbase + (y0 + oy) * 64 + x0 + xo) * CC + cbase + dp * 2;
            unsigned ap = *(const unsigned*)(attb + g);
            float at0 = __uint_as_float(ap << 16);
            float at1 = __uint_as_float(ap & 0xffff0000u);
            unsigned short o0 = (unsigned short)f2bf(a0[xo] + at0);
            unsigned short o1 = (unsigned short)f2bf(a1[xo] + at1);
            *(unsigned*)(xb + g) = (unsigned)o0 | ((unsigned)o1 << 16);
        }
    }
}

extern "C" void kernel_launch(void* const* d_in, const int* in_sizes, int n_in,
                              void* d_out, int out_size, void* d_ws, size_t ws_size,
                              hipStream_t stream) {
    (void)in_sizes; (void)n_in; (void)out_size; (void)ws_size;
    const float* x1    = (const float*)d_in[0];
    const float* x2    = (const float*)d_in[1];
    const float* Wq    = (const float*)d_in[2];
    const float* Wkv   = (const float*)d_in[3];
    const float* Wproj = (const float*)d_in[4];
    const float* bproj = (const float*)d_in[5];
    const float* dwcw  = (const float*)d_in[6];
    const float* dwcb  = (const float*)d_in[7];
    const float* scale = (const float*)d_in[8];
    const float* pos   = (const float*)d_in[9];
    float* out = (float*)d_out;

    const size_t MC = (size_t)CM * CC;   // 20,971,520 elems
    unsigned short* ws16 = (unsigned short*)d_ws;
    // region A [0, MC): x1bf -> kv2p(f32, 21MB) -> attbf
    unsigned short* x1bf  = ws16;
    float*          kv2p  = (float*)ws16;
    unsigned short* attbf = ws16;
    // region B [MC, 2MC): x2bf -> ktbf -> xbf
    unsigned short* x2bf = ws16 + MC;
    unsigned short* ktbf = x2bf;
    unsigned short* xbf  = x2bf;
    // region C [2MC, 3MC): vbf (live through dwconv2)
    unsigned short* vbf  = ws16 + 2 * MC;
    // region D [3MC, 4MC): qtbf
    unsigned short* qtbf = ws16 + 3 * MC;
    // tail
    unsigned short* kv2bf = ws16 + 4 * MC;                          // 40*16384 bf16
    float* ksmp = (float*)(kv2bf + (size_t)40 * 16384);             // 40*8*2*64 f32
    float* ksm  = ksmp + (size_t)40 * NCH * 128;                    // 40*128
    float* scb  = ksm + (size_t)40 * 128;                           // 640
    unsigned short* Wqbf    = (unsigned short*)(scb + 640);         // 640*640
    unsigned short* Wkvbf   = Wqbf + (size_t)CC * CC;               // 1280*640
    unsigned short* Wprojbf = Wkvbf + (size_t)2 * CC * CC;          // 640*640
    // kq GEMM output lives in d_out as bf16 [M][1280] (exactly fills it)
    unsigned short* kqbf = (unsigned short*)d_out;

    hipLaunchKernelGGL(softplus_k, dim3(1), dim3(640), 0, stream, scale, scb);
    hipLaunchKernelGGL(cvt_bf16, dim3(2048), dim3(256), 0, stream, x1, x1bf, (int)(MC / 8));
    hipLaunchKernelGGL(cvt_bf16, dim3(2048), dim3(256), 0, stream, x2, x2bf, (int)(MC / 8));
    hipLaunchKernelGGL(cvt_bf16, dim3(64),  dim3(256), 0, stream, Wq,    Wqbf,    CC * CC / 8);
    hipLaunchKernelGGL(cvt_bf16, dim3(128), dim3(256), 0, stream, Wkv,   Wkvbf,   2 * CC * CC / 8);
    hipLaunchKernelGGL(cvt_bf16, dim3(64),  dim3(256), 0, stream, Wproj, Wprojbf, CC * CC / 8);

    hipLaunchKernelGGL((gemm_bf16b<false, true>), dim3(CC/128, CM/128), dim3(256), 0, stream,
                       x2bf, Wqbf, (void*)vbf, (const float*)nullptr, CC, CC);
    hipLaunchKernelGGL((gemm_bf16b<false, true>), dim3(1280/128, CM/128), dim3(256), 0, stream,
                       x1bf, Wkvbf, (void*)kqbf, (const float*)nullptr, CC, 1280);
    hipLaunchKernelGGL(rowtrans2, dim3(CM/4), dim3(256), 0, stream, kqbf, pos, scb, qtbf, ktbf);
    hipLaunchKernelGGL(kv2_partial, dim3(NCH, 40, 4), dim3(256), 0, stream, ktbf, vbf, kv2p, ksmp);
    hipLaunchKernelGGL(kv2_reduce, dim3(40), dim3(256), 0, stream, kv2p, ksmp, kv2bf, ksm);
    hipLaunchKernelGGL(attn_mfma, dim3(CN/128, 40), dim3(256), 0, stream, qtbf, kv2bf, ksm, attbf);
    hipLaunchKernelGGL(dwconv2, dim3(8, 4, 40), dim3(256), 0, stream, vbf, attbf, dwcw, dwcb, xbf);
    hipLaunchKernelGGL((gemm_bf16b<true, false>), dim3(CC/128, CM/128), dim3(256), 0, stream,
                       xbf, Wprojbf, (void*)out, bproj, CC, CC);
}

// Round 9
// 507.495 us; speedup vs baseline: 4.0957x; 1.0566x over previous
//
#include <hip/hip_runtime.h>
#include <math.h>

constexpr int CB  = 8;       // batch
constexpr int CN  = 4096;    // tokens
constexpr int CC  = 640;     // channels
constexpr int CNH = 5;       // heads
constexpr int CHD = 128;     // head dim
constexpr int CM  = CB * CN; // 32768 rows
constexpr float CEPS = 1e-6f;
constexpr int NCH = 8;       // token chunks for kv2 partials

typedef __attribute__((ext_vector_type(8))) short bf16x8;
typedef __attribute__((ext_vector_type(4))) float f32x4;

typedef __attribute__((address_space(1))) const unsigned int gas_u32;
typedef __attribute__((address_space(3))) unsigned int las_u32;

__device__ __forceinline__ void gload16(const void* g, void* l) {
    __builtin_amdgcn_global_load_lds((gas_u32*)g, (las_u32*)l, 16, 0, 0);
}

__device__ __forceinline__ short f2bf(float x) {
    unsigned u = __float_as_uint(x);
    unsigned r = (u + 0x7fffu + ((u >> 16) & 1u)) >> 16;   // RNE, finite data
    return (short)r;
}
__device__ __forceinline__ float b2f(unsigned short u) {
    return __uint_as_float(((unsigned)u) << 16);
}

// ---------------- softplus of scale ----------------
__global__ void softplus_k(const float* __restrict__ scale, float* __restrict__ sc) {
    int t = threadIdx.x;
    if (t < CC) sc[t] = log1pf(expf(scale[t]));
}

// ---------------- f32 -> bf16 cvt, 8 elems/thread grid-stride ----------------
__global__ __launch_bounds__(256) void cvt_bf16(const float* __restrict__ src,
                                                unsigned short* __restrict__ dst, int n8) {
    int i = blockIdx.x * 256 + threadIdx.x;
    const int stride = gridDim.x * 256;
    for (; i < n8; i += stride) {
        float4 f0 = *(const float4*)(src + (size_t)i * 8);
        float4 f1 = *(const float4*)(src + (size_t)i * 8 + 4);
        bf16x8 h;
        h[0]=f2bf(f0.x); h[1]=f2bf(f0.y); h[2]=f2bf(f0.z); h[3]=f2bf(f0.w);
        h[4]=f2bf(f1.x); h[5]=f2bf(f1.y); h[6]=f2bf(f1.z); h[7]=f2bf(f1.w);
        *(bf16x8*)(dst + (size_t)i * 8) = h;
    }
}

// ------- bf16 MFMA GEMM: C[M,N] = A[M,K]*B[N,K]^T (+bias), bf16 in, bf16/f32 out -------
// 128x128 tile, BK=32, 4 waves, double-buffered LDS, global_load_lds(16B) w/ pre-swizzled src.
// XCD-AWARE SWIZZLE (T1): wgid%8 = XCD (HW round-robin). All n-panels of one A-panel map
// to the same XCD, consecutively -> A-panel fetched once per XCD instead of ~4-8x.
// Requires gridDim.y (m-panels) % 8 == 0.
template<bool BIAS, bool OUTBF>
__global__ __launch_bounds__(256) void gemm_bf16b(const unsigned short* __restrict__ Abf,
                                                  const unsigned short* __restrict__ Bbf,
                                                  void* __restrict__ Co,
                                                  const float* __restrict__ bias,
                                                  int Kr, int Nr) {
    __shared__ unsigned short lA[2][4096];
    __shared__ unsigned short lB[2][4096];
    const int t  = threadIdx.x;
    const int npan = gridDim.x;                    // N/128
    const int mper = gridDim.y >> 3;               // m-panels per XCD
    const int wg   = blockIdx.y * npan + blockIdx.x;
    const int xcd  = wg & 7;
    const int j    = wg >> 3;
    const int m0 = (xcd * mper + j / npan) * 128;
    const int n0 = (j % npan) * 128;
    const int l  = t & 63, w = t >> 6, wr = w >> 1, wc = w & 1;

    // per-lane source chunks (chunk = 16B = 8 bf16); inverse of read-side XOR
    const int cp0 = w * 64 + l;
    const int cp1 = cp0 + 256;
    const int s0 = cp0 ^ (((cp0 >> 2) & 7) ^ ((cp0 >> 4) & 1));
    const int s1 = cp1 ^ (((cp1 >> 2) & 7) ^ ((cp1 >> 4) & 1));
    const size_t gA0 = (size_t)(m0 + (s0 >> 2)) * Kr + (s0 & 3) * 8;
    const size_t gA1 = (size_t)(m0 + (s1 >> 2)) * Kr + (s1 & 3) * 8;
    const size_t gB0 = (size_t)(n0 + (s0 >> 2)) * Kr + (s0 & 3) * 8;
    const size_t gB1 = (size_t)(n0 + (s1 >> 2)) * Kr + (s1 & 3) * 8;
    const int dA0 = w * 512;          // LDS elem offset, call 0
    const int dA1 = 2048 + w * 512;   // call 1

    const int offA = ((wr * 64 + (l & 15)) * 64 + (l >> 4) * 16) ^ ((l & 7) << 4);
    const int offB = ((wc * 64 + (l & 15)) * 64 + (l >> 4) * 16) ^ ((l & 7) << 4);

    f32x4 acc[4][4];
    #pragma unroll
    for (int i = 0; i < 4; ++i)
        #pragma unroll
        for (int j2 = 0; j2 < 4; ++j2) acc[i][j2] = (f32x4){0.f, 0.f, 0.f, 0.f};

    // prologue: stage tile 0 into buf 0
    gload16(Abf + gA0, &lA[0][dA0]);
    gload16(Abf + gA1, &lA[0][dA1]);
    gload16(Bbf + gB0, &lB[0][dA0]);
    gload16(Bbf + gB1, &lB[0][dA1]);
    __syncthreads();

    int cur = 0;
    for (int k0 = 0; k0 < Kr; k0 += 32) {
        if (k0 + 32 < Kr) {   // stage next tile into the other buffer
            const int nb = cur ^ 1;
            gload16(Abf + gA0 + k0 + 32, &lA[nb][dA0]);
            gload16(Abf + gA1 + k0 + 32, &lA[nb][dA1]);
            gload16(Bbf + gB0 + k0 + 32, &lB[nb][dA0]);
            gload16(Bbf + gB1 + k0 + 32, &lB[nb][dA1]);
        }
        bf16x8 af[4], bfv[4];
        #pragma unroll
        for (int i = 0; i < 4; ++i) {
            af[i]  = *(const bf16x8*)((const char*)&lA[cur][0] + offA + i * 1024);
            bfv[i] = *(const bf16x8*)((const char*)&lB[cur][0] + offB + i * 1024);
        }
        #pragma unroll
        for (int i = 0; i < 4; ++i)
            #pragma unroll
            for (int j2 = 0; j2 < 4; ++j2)
                acc[i][j2] = __builtin_amdgcn_mfma_f32_16x16x32_bf16(af[i], bfv[j2], acc[i][j2], 0, 0, 0);
        __syncthreads();   // drains vmcnt(0): next buf staged; all reads of cur done
        cur ^= 1;
    }

    #pragma unroll
    for (int j2 = 0; j2 < 4; ++j2) {
        const int n = n0 + wc * 64 + j2 * 16 + (l & 15);
        const float bv = BIAS ? bias[n] : 0.f;
        #pragma unroll
        for (int i = 0; i < 4; ++i) {
            const int m = m0 + wr * 64 + i * 16 + (l >> 4) * 4;
            #pragma unroll
            for (int r = 0; r < 4; ++r) {
                float val = acc[i][j2][r] + bv;
                if (OUTBF) ((unsigned short*)Co)[(size_t)(m + r) * Nr + n] = (unsigned short)f2bf(val);
                else       ((float*)Co)[(size_t)(m + r) * Nr + n] = val;
            }
        }
    }
}

// ------- per-row focused transform: one row per WAVE, shfl-only reduce -------
// kq layout: [m][1280], cols 0..639 = k (Wkv rows 0..639), 640..1279 = q.
__global__ __launch_bounds__(256) void rowtrans2(const unsigned short* __restrict__ kq,
                                                 const float* __restrict__ pos,
                                                 const float* __restrict__ sc,
                                                 unsigned short* __restrict__ qt,
                                                 unsigned short* __restrict__ kt) {
    const int w = threadIdx.x >> 6, l = threadIdx.x & 63;
    const int m = blockIdx.x * 4 + w;
    const int n = m & (CN - 1);
    const unsigned short* rowk = kq + (size_t)m * 1280;
    const unsigned short* rowq = rowk + 640;
    float qv[10], kv[10];
    float s2q = 0.f, s6q = 0.f, s2k = 0.f, s6k = 0.f;
    #pragma unroll
    for (int j = 0; j < 10; ++j) {
        const int c = l + 64 * j;
        const float scv = sc[c];
        float qq = (fmaxf(b2f(rowq[c]), 0.f) + CEPS) / scv;
        float kk = (fmaxf(b2f(rowk[c]) + pos[(size_t)n * CC + c], 0.f) + CEPS) / scv;
        qv[j] = qq; kv[j] = kk;
        const float q2 = qq * qq, k2 = kk * kk;
        s2q += q2; s6q += q2 * q2 * q2;
        s2k += k2; s6k += k2 * k2 * k2;
    }
    #pragma unroll
    for (int o = 32; o > 0; o >>= 1) {
        s2q += __shfl_xor(s2q, o);
        s6q += __shfl_xor(s6q, o);
        s2k += __shfl_xor(s2k, o);
        s6k += __shfl_xor(s6k, o);
    }
    const float qmul = sqrtf(s2q) / sqrtf(s6q);
    const float kmul = sqrtf(s2k) / sqrtf(s6k);
    #pragma unroll
    for (int j = 0; j < 10; ++j) {
        const int c = l + 64 * j;
        qt[(size_t)m * CC + c] = (unsigned short)f2bf(qv[j] * qv[j] * qv[j] * qmul);
        kt[(size_t)m * CC + c] = (unsigned short)f2bf(kv[j] * kv[j] * kv[j] * kmul);
    }
}

// ------- kv2 partials, QUADRANT split: per (nc, bh, q): 64x64 of K^T V over 512 rows -------
__global__ __launch_bounds__(256) void kv2_partial(const unsigned short* __restrict__ kt,
                                                   const unsigned short* __restrict__ vb,
                                                   float* __restrict__ kv2p,
                                                   float* __restrict__ ksmp) {
    const int nc = blockIdx.x, bh = blockIdx.y, q = blockIdx.z;
    const int qc = q & 1, qd = q >> 1;
    const int b = bh / CNH, h = bh % CNH;
    __shared__ float ks[32][68];
    __shared__ float vs[32][68];
    const int t = threadIdx.x;
    const int tx = t & 15, ty = t >> 4;
    float acc[4][4];
    #pragma unroll
    for (int i = 0; i < 4; ++i)
        #pragma unroll
        for (int j = 0; j < 4; ++j) acc[i][j] = 0.f;
    float ksacc = 0.f;
    const size_t mbase = (size_t)b * CN + (size_t)nc * 512;
    const int cofK = h * CHD + qc * 64;
    const int cofV = h * CHD + qd * 64;
    const int token = t >> 3, c8 = (t & 7) * 8;
    for (int tile = 0; tile < 16; ++tile) {
        const int nt0 = tile * 32;
        __syncthreads();
        {
            const size_t r = (mbase + nt0 + token) * CC;
            bf16x8 hk = *(const bf16x8*)(kt + r + cofK + c8);
            bf16x8 hv = *(const bf16x8*)(vb + r + cofV + c8);
            float4 k0, k1, v0, v1;
            k0.x=b2f(hk[0]); k0.y=b2f(hk[1]); k0.z=b2f(hk[2]); k0.w=b2f(hk[3]);
            k1.x=b2f(hk[4]); k1.y=b2f(hk[5]); k1.z=b2f(hk[6]); k1.w=b2f(hk[7]);
            v0.x=b2f(hv[0]); v0.y=b2f(hv[1]); v0.z=b2f(hv[2]); v0.w=b2f(hv[3]);
            v1.x=b2f(hv[4]); v1.y=b2f(hv[5]); v1.z=b2f(hv[6]); v1.w=b2f(hv[7]);
            *(float4*)&ks[token][c8]     = k0;
            *(float4*)&ks[token][c8 + 4] = k1;
            *(float4*)&vs[token][c8]     = v0;
            *(float4*)&vs[token][c8 + 4] = v1;
        }
        __syncthreads();
        #pragma unroll 4
        for (int nn = 0; nn < 32; ++nn) {
            float4 av = *(const float4*)&ks[nn][ty * 4];
            float4 bv = *(const float4*)&vs[nn][tx * 4];
            float a[4] = {av.x, av.y, av.z, av.w};
            float bb[4] = {bv.x, bv.y, bv.z, bv.w};
            #pragma unroll
            for (int i = 0; i < 4; ++i)
                #pragma unroll
                for (int j = 0; j < 4; ++j)
                    acc[i][j] = fmaf(a[i], bb[j], acc[i][j]);
        }
        if (qd == 0 && t < 64) {
            #pragma unroll
            for (int nn = 0; nn < 32; ++nn) ksacc += ks[nn][t];
        }
    }
    float* outp = kv2p + (((size_t)bh * NCH + nc) * 4 + q) * 4096;
    #pragma unroll
    for (int i = 0; i < 4; ++i) {
        float4 o;
        o.x = acc[i][0]; o.y = acc[i][1]; o.z = acc[i][2]; o.w = acc[i][3];
        *(float4*)&outp[(ty * 4 + i) * 64 + tx * 4] = o;
    }
    if (qd == 0 && t < 64)
        ksmp[(((size_t)bh * NCH + nc) * 2 + qc) * 64 + t] = ksacc;
}

// ------- reduce partials; emit kv2^T as bf16 [d][c] + ksum f32 -------
__global__ __launch_bounds__(256) void kv2_reduce(const float* __restrict__ kv2p,
                                                  const float* __restrict__ ksmp,
                                                  unsigned short* __restrict__ kv2bf,
                                                  float* __restrict__ ksm) {
    const int bh = blockIdx.x, t = threadIdx.x;
    for (int o = t; o < 16384; o += 256) {
        const int d = o >> 7, c = o & 127;
        const int q = (d >> 6) * 2 + (c >> 6);
        float s = 0.f;
        #pragma unroll
        for (int nc = 0; nc < NCH; ++nc)
            s += kv2p[(((size_t)bh * NCH + nc) * 4 + q) * 4096 + (c & 63) * 64 + (d & 63)];
        kv2bf[(size_t)bh * 16384 + o] = (unsigned short)f2bf(s);
    }
    if (t < 128) {
        float s = 0.f;
        #pragma unroll
        for (int nc = 0; nc < NCH; ++nc)
            s += ksmp[(((size_t)bh * NCH + nc) * 2 + (t >> 6)) * 64 + (t & 63)];
        ksm[(size_t)bh * 128 + t] = s;
    }
}

// ------- attention out via MFMA: att = (q@kv2)*z, bf16 in/out -------
__global__ __launch_bounds__(256) void attn_mfma(const unsigned short* __restrict__ qt,
                                                 const unsigned short* __restrict__ kv2bf,
                                                 const float* __restrict__ ksm,
                                                 unsigned short* __restrict__ attb) {
    const int nb = blockIdx.x, bh = blockIdx.y;
    const int b = bh / CNH, h = bh % CNH;
    __shared__ short lQ[16384];    // 128 x 128 bf16, swizzled
    __shared__ short lKV[16384];   // [d][c] bf16, swizzled
    __shared__ float zs[128];
    const int t = threadIdx.x;
    const int l = t & 63, w = t >> 6, wr = w >> 1, wc = w & 1;
    const size_t m0 = (size_t)b * CN + (size_t)nb * 128;

    const int srow0 = t >> 4;      // 0..15
    const int c16   = t & 15;      // 16B chunk within row
    float kreg[8];
    {
        const float* kp = ksm + (size_t)bh * 128 + c16 * 8;
        float4 k0 = *(const float4*)kp, k1 = *(const float4*)(kp + 4);
        kreg[0]=k0.x; kreg[1]=k0.y; kreg[2]=k0.z; kreg[3]=k0.w;
        kreg[4]=k1.x; kreg[5]=k1.y; kreg[6]=k1.z; kreg[7]=k1.w;
    }
    #pragma unroll
    for (int p = 0; p < 8; ++p) {
        const int row = srow0 + p * 16;
        const int st = (row * 256 + c16 * 16) ^ ((row & 7) << 4);
        bf16x8 hq = *(const bf16x8*)(qt + (m0 + row) * CC + h * CHD + c16 * 8);
        *(bf16x8*)((char*)lQ + st) = hq;
        float zp = 0.f;
        #pragma unroll
        for (int j = 0; j < 8; ++j) zp = fmaf(b2f((unsigned short)hq[j]), kreg[j], zp);
        zp += __shfl_xor(zp, 1);
        zp += __shfl_xor(zp, 2);
        zp += __shfl_xor(zp, 4);
        zp += __shfl_xor(zp, 8);
        if (c16 == 0) zs[row] = 1.f / (zp + CEPS);
        bf16x8 hk = *(const bf16x8*)(kv2bf + (size_t)bh * 16384 + row * 128 + c16 * 8);
        *(bf16x8*)((char*)lKV + st) = hk;
    }
    __syncthreads();

    const int baseA = (wr * 64 + (l & 15)) * 256 + ((l >> 4) << 4);
    const int baseB = (wc * 64 + (l & 15)) * 256 + ((l >> 4) << 4);
    const int xorv  = (l & 7) << 4;
    f32x4 acc[4][4];
    #pragma unroll
    for (int i = 0; i < 4; ++i)
        #pragma unroll
        for (int j = 0; j < 4; ++j) acc[i][j] = (f32x4){0.f, 0.f, 0.f, 0.f};

    #pragma unroll
    for (int kk = 0; kk < 4; ++kk) {
        bf16x8 af[4], bv[4];
        #pragma unroll
        for (int i = 0; i < 4; ++i) {
            af[i] = *(const bf16x8*)((const char*)lQ  + (((baseA + kk * 64) ^ xorv) + i * 4096));
            bv[i] = *(const bf16x8*)((const char*)lKV + (((baseB + kk * 64) ^ xorv) + i * 4096));
        }
        #pragma unroll
        for (int i = 0; i < 4; ++i)
            #pragma unroll
            for (int j = 0; j < 4; ++j)
                acc[i][j] = __builtin_amdgcn_mfma_f32_16x16x32_bf16(af[i], bv[j], acc[i][j], 0, 0, 0);
    }

    #pragma unroll
    for (int i = 0; i < 4; ++i) {
        const int mBase = wr * 64 + i * 16 + (l >> 4) * 4;
        float zv[4];
        #pragma unroll
        for (int r = 0; r < 4; ++r) zv[r] = zs[mBase + r];
        #pragma unroll
        for (int j = 0; j < 4; ++j) {
            const int n = wc * 64 + j * 16 + (l & 15);
            unsigned short* op = attb + (m0 + mBase) * CC + h * CHD + n;
            #pragma unroll
            for (int r = 0; r < 4; ++r)
                op[(size_t)r * CC] = (unsigned short)f2bf(acc[i][j][r] * zv[r]);
        }
    }
}

// ------- LDS-tiled 5x5 depthwise conv: x = att + conv(v) + bias, bf16 in/out -------
__global__ __launch_bounds__(256) void dwconv2(const unsigned short* __restrict__ vb,
                                               const unsigned short* __restrict__ attb,
                                               const float* __restrict__ w,
                                               const float* __restrict__ bias,
                                               unsigned short* __restrict__ xb) {
    const int yt = blockIdx.x;      // 0..7
    const int dq = blockIdx.y;      // 0..3
    const int bh = blockIdx.z;      // 0..39
    const int b = bh / CNH, h = bh % CNH;
    __shared__ unsigned short vt[12 * 68 * 32];
    const int t = threadIdx.x;
    const int y0 = yt * 8;
    const size_t rowbase = (size_t)b * CN;
    const int cbase = h * CHD + dq * 32;
    for (int c = t; c < 3264; c += 256) {
        int pos = c >> 2, d8 = (c & 3) * 8;
        int ly = pos / 68, lx = pos - ly * 68;
        int yy = y0 - 2 + ly, xx = lx - 2;
        bf16x8 val = (bf16x8){0,0,0,0,0,0,0,0};
        if (yy >= 0 && yy < 64 && xx >= 0 && xx < 64)
            val = *(const bf16x8*)(vb + (rowbase + yy * 64 + xx) * CC + cbase + d8);
        *(bf16x8*)(vt + pos * 32 + d8) = val;
    }
    __syncthreads();
    const int dp = t & 15;
    const int xg = t >> 4;
    const int d0 = dq * 32 + dp * 2;            // head-dim channel in [0,128)
    float wr0[25], wr1[25];
    #pragma unroll
    for (int i = 0; i < 25; ++i) {
        wr0[i] = w[d0 * 25 + i];
        wr1[i] = w[(d0 + 1) * 25 + i];
    }
    const float bv0 = bias[d0], bv1 = bias[d0 + 1];
    const int x0 = xg * 4;
    for (int oy = 0; oy < 8; ++oy) {
        float a0[4] = {bv0, bv0, bv0, bv0}, a1[4] = {bv1, bv1, bv1, bv1};
        #pragma unroll
        for (int dy = 0; dy < 5; ++dy) {
            const unsigned short* rp = vt + ((oy + dy) * 68 + x0) * 32 + dp * 2;
            float v0[8], v1[8];
            #pragma unroll
            for (int j = 0; j < 8; ++j) {
                unsigned pr = *(const unsigned*)(rp + j * 32);
                v0[j] = __uint_as_float(pr << 16);
                v1[j] = __uint_as_float(pr & 0xffff0000u);
            }
            #pragma unroll
            for (int dx = 0; dx < 5; ++dx) {
                const float w0 = wr0[dy * 5 + dx], w1 = wr1[dy * 5 + dx];
                #pragma unroll
                for (int xo = 0; xo < 4; ++xo) {
                    a0[xo] = fmaf(w0, v0[xo + dx], a0[xo]);
                    a1[xo] = fmaf(w1, v1[xo + dx], a1[xo]);
                }
            }
        }
        #pragma unroll
        for (int xo = 0; xo < 4; ++xo) {
            size_t g = (rowbase + (y0 + oy) * 64 + x0 + xo) * CC + cbase + dp * 2;
            unsigned ap = *(const unsigned*)(attb + g);
            float at0 = __uint_as_float(ap << 16);
            float at1 = __uint_as_float(ap & 0xffff0000u);
            unsigned short o0 = (unsigned short)f2bf(a0[xo] + at0);
            unsigned short o1 = (unsigned short)f2bf(a1[xo] + at1);
            *(unsigned*)(xb + g) = (unsigned)o0 | ((unsigned)o1 << 16);
        }
    }
}

extern "C" void kernel_launch(void* const* d_in, const int* in_sizes, int n_in,
                              void* d_out, int out_size, void* d_ws, size_t ws_size,
                              hipStream_t stream) {
    (void)in_sizes; (void)n_in; (void)out_size; (void)ws_size;
    const float* x1    = (const float*)d_in[0];
    const float* x2    = (const float*)d_in[1];
    const float* Wq    = (const float*)d_in[2];
    const float* Wkv   = (const float*)d_in[3];
    const float* Wproj = (const float*)d_in[4];
    const float* bproj = (const float*)d_in[5];
    const float* dwcw  = (const float*)d_in[6];
    const float* dwcb  = (const float*)d_in[7];
    const float* scale = (const float*)d_in[8];
    const float* pos   = (const float*)d_in[9];
    float* out = (float*)d_out;

    const size_t MC = (size_t)CM * CC;   // 20,971,520 elems
    unsigned short* ws16 = (unsigned short*)d_ws;
    // region A [0, MC): x1bf -> kv2p(f32, 21MB) -> attbf
    unsigned short* x1bf  = ws16;
    float*          kv2p  = (float*)ws16;
    unsigned short* attbf = ws16;
    // region B [MC, 2MC): x2bf -> ktbf -> xbf
    unsigned short* x2bf = ws16 + MC;
    unsigned short* ktbf = x2bf;
    unsigned short* xbf  = x2bf;
    // region C [2MC, 3MC): vbf (live through dwconv2)
    unsigned short* vbf  = ws16 + 2 * MC;
    // region D [3MC, 4MC): qtbf
    unsigned short* qtbf = ws16 + 3 * MC;
    // tail
    unsigned short* kv2bf = ws16 + 4 * MC;                          // 40*16384 bf16
    float* ksmp = (float*)(kv2bf + (size_t)40 * 16384);             // 40*8*2*64 f32
    float* ksm  = ksmp + (size_t)40 * NCH * 128;                    // 40*128
    float* scb  = ksm + (size_t)40 * 128;                           // 640
    unsigned short* Wqbf    = (unsigned short*)(scb + 640);         // 640*640
    unsigned short* Wkvbf   = Wqbf + (size_t)CC * CC;               // 1280*640
    unsigned short* Wprojbf = Wkvbf + (size_t)2 * CC * CC;          // 640*640
    // kq GEMM output lives in d_out as bf16 [M][1280] (exactly fills it)
    unsigned short* kqbf = (unsigned short*)d_out;

    hipLaunchKernelGGL(softplus_k, dim3(1), dim3(640), 0, stream, scale, scb);
    hipLaunchKernelGGL(cvt_bf16, dim3(2048), dim3(256), 0, stream, x1, x1bf, (int)(MC / 8));
    hipLaunchKernelGGL(cvt_bf16, dim3(2048), dim3(256), 0, stream, x2, x2bf, (int)(MC / 8));
    hipLaunchKernelGGL(cvt_bf16, dim3(64),  dim3(256), 0, stream, Wq,    Wqbf,    CC * CC / 8);
    hipLaunchKernelGGL(cvt_bf16, dim3(128), dim3(256), 0, stream, Wkv,   Wkvbf,   2 * CC * CC / 8);
    hipLaunchKernelGGL(cvt_bf16, dim3(64),  dim3(256), 0, stream, Wproj, Wprojbf, CC * CC / 8);

    hipLaunchKernelGGL((gemm_bf16b<false, true>), dim3(CC/128, CM/128), dim3(256), 0, stream,
                       x2bf, Wqbf, (void*)vbf, (const float*)nullptr, CC, CC);
    hipLaunchKernelGGL((gemm_bf16b<false, true>), dim3(1280/128, CM/128), dim3(256), 0, stream,
                       x1bf, Wkvbf, (void*)kqbf, (const float*)nullptr, CC, 1280);
    hipLaunchKernelGGL(rowtrans2, dim3(CM/4), dim3(256), 0, stream, kqbf, pos, scb, qtbf, ktbf);
    hipLaunchKernelGGL(kv2_partial, dim3(NCH, 40, 4), dim3(256), 0, stream, ktbf, vbf, kv2p, ksmp);
    hipLaunchKernelGGL(kv2_reduce, dim3(40), dim3(256), 0, stream, kv2p, ksmp, kv2bf, ksm);
    hipLaunchKernelGGL(attn_mfma, dim3(CN/128, 40), dim3(256), 0, stream, qtbf, kv2bf, ksm, attbf);
    hipLaunchKernelGGL(dwconv2, dim3(8, 4, 40), dim3(256), 0, stream, vbf, attbf, dwcw, dwcb, xbf);
    hipLaunchKernelGGL((gemm_bf16b<true, false>), dim3(CC/128, CM/128), dim3(256), 0, stream,
                       xbf, Wprojbf, (void*)out, bproj, CC, CC);
}